// Round 17
// baseline (83.767 us; speedup 1.0000x reference)
//
#include <hip/hip_runtime.h>
#include <hip/hip_bf16.h>

#define N_TOK 8192

typedef float f32x4  __attribute__((ext_vector_type(4)));
typedef float f32x16 __attribute__((ext_vector_type(16)));
typedef short bf16x8 __attribute__((ext_vector_type(8)));
typedef unsigned int u32x4 __attribute__((ext_vector_type(4)));

__device__ inline short f2bf(float f) {
    union { __hip_bfloat16 h; short s; } u;
    u.h = __float2bfloat16(f);
    return u.s;
}
__device__ inline unsigned cvtpk(float lo, float hi) {
    unsigned r;
    asm("v_cvt_pk_bf16_f32 %0, %1, %2" : "=v"(r) : "v"(lo), "v"(hi));
    return r;
}
__device__ inline void plswap(unsigned &a, unsigned &b) {
    asm("v_permlane32_swap_b32 %0, %1" : "+v"(a), "+v"(b));
}

#define PREC 2080   // f32 per partial record: 2048 O (d-major [64][32]) + 32 l

// Fragment-major tensor layouts (all 1 MiB):
//  Qf[((t*4 + kc)*64 + lane)*8 + j]      : Q[t*32 + (lane&31)][kc*16 + 8*(lane>>5) + j]
//  Kf[((c*8 + 4*hk + kc)*64 + lane)*8+j] : K[c*64 + 32*hk + (lane&31)][kc*16 + 8*(lane>>5) + j]
//  Vf[((c*8 + 4*hd + ks)*64 + lane)*8+j] : V[c*64 + ks*16 + 8*(lane>>5) + j][32*hd + (lane&31)]

// ---------------- kernel 0: weight convert/transpose (LDS tiled) ----
__global__ __launch_bounds__(256) void conv_kernel(
    const float* __restrict__ Wqkv,
    const float* __restrict__ Wout,
    __hip_bfloat16* __restrict__ Wt,      // [192][1024]
    __hip_bfloat16* __restrict__ WoT) {   // [1024][64]
    __shared__ float tile[32][33];
    const int t = threadIdx.x;
    const int cc = t & 31, rbase = t >> 5;
    const int b = blockIdx.x;
    if (b < 192) {
        const int r0 = (b & 31) * 32;   // k
        const int c0 = (b >> 5) * 32;   // n
        #pragma unroll
        for (int it = 0; it < 4; ++it) {
            const int rr = rbase + it * 8;
            tile[rr][cc] = Wqkv[(size_t)(r0 + rr) * 192 + c0 + cc];
        }
        __syncthreads();
        #pragma unroll
        for (int it = 0; it < 4; ++it) {
            const int rr = rbase + it * 8;
            Wt[(size_t)(c0 + rr) * 1024 + r0 + cc] = __float2bfloat16(tile[cc][rr]);
        }
    } else {
        const int bb = b - 192;
        const int r0 = (bb & 1) * 32;   // k (rows of Wout)
        const int c0 = (bb >> 1) * 32;  // n
        #pragma unroll
        for (int it = 0; it < 4; ++it) {
            const int rr = rbase + it * 8;
            tile[rr][cc] = Wout[(size_t)(r0 + rr) * 1024 + c0 + cc];
        }
        __syncthreads();
        #pragma unroll
        for (int it = 0; it < 4; ++it) {
            const int rr = rbase + it * 8;
            WoT[(size_t)(c0 + rr) * 64 + r0 + cc] = __float2bfloat16(tile[cc][rr]);
        }
    }
}

// ---------------- kernel 1: qkv = x @ Wqkv -------------------------
// LDS-staged double-buffered GEMM. BM=16, BN=192, BK=64, grid 512,
// 256 thr (4 waves) -> 2 independent blocks/CU (barrier overlap).
// Epilogue writes Qf/Kf/Vf in MFMA-fragment-major layout.
__global__ __launch_bounds__(256) void qkv_kernel(
    const float* __restrict__ x,
    const __hip_bfloat16* __restrict__ Wt,   // [192][1024]
    __hip_bfloat16* __restrict__ Qf,
    __hip_bfloat16* __restrict__ Kf,
    __hip_bfloat16* __restrict__ Vf) {
    __shared__ __hip_bfloat16 sA[2][16 * 64];
    __shared__ __hip_bfloat16 sB[2][192 * 64];
    __shared__ __hip_bfloat16 sV[64][20];
    const int tid = threadIdx.x;
    const int w = tid >> 6, lane = tid & 63;
    const int l16 = lane & 15, lq = lane >> 4;
    const int m0 = blockIdx.x * 16;

    // staging thread-constants
    const int ar = tid >> 4;                 // x row 0..15
    const int ac = (tid & 15) >> 1;          // chunk 0..7
    const int ah = tid & 1;                  // half-chunk
    const float* agp = x + (size_t)(m0 + ar) * 1024 + ac * 8 + ah * 4;
    const int aoff = ar * 64 + ((ac ^ (ar & 7)) * 8) + ah * 4;

    int boff[6];
    const __hip_bfloat16* bgp[6];
    #pragma unroll
    for (int i = 0; i < 6; ++i) {
        const int q = i * 256 + tid;
        const int r = q >> 3, c = q & 7;
        bgp[i] = Wt + (size_t)r * 1024 + c * 8;
        boff[i] = r * 64 + ((c ^ (r & 7)) * 8);
    }

    // fragment read offsets (swizzled)
    const int arow = l16;
    const int aswz0 = arow * 64 + ((lq ^ (arow & 7)) * 8);
    const int aswz1 = arow * 64 + (((4 + lq) ^ (arow & 7)) * 8);
    int bswz0[3], bswz1[3];
    #pragma unroll
    for (int j = 0; j < 3; ++j) {
        const int row = (w * 3 + j) * 16 + l16;
        bswz0[j] = row * 64 + ((lq ^ (row & 7)) * 8);
        bswz1[j] = row * 64 + (((4 + lq) ^ (row & 7)) * 8);
    }

    f32x4 acc[3];
    #pragma unroll
    for (int j = 0; j < 3; ++j) acc[j] = (f32x4)0.f;

    float4 areg;
    u32x4 breg[6];

    areg = *reinterpret_cast<const float4*>(agp);
    #pragma unroll
    for (int i = 0; i < 6; ++i)
        breg[i] = *reinterpret_cast<const u32x4*>(bgp[i]);
    {
        uint2 aw; aw.x = cvtpk(areg.x, areg.y); aw.y = cvtpk(areg.z, areg.w);
        *reinterpret_cast<uint2*>(&sA[0][aoff]) = aw;
        #pragma unroll
        for (int i = 0; i < 6; ++i)
            *reinterpret_cast<u32x4*>(&sB[0][boff[i]]) = breg[i];
    }
    __syncthreads();

    for (int ks = 0; ks < 16; ++ks) {
        const int cur = ks & 1;
        if (ks < 15) {
            areg = *reinterpret_cast<const float4*>(agp + (ks + 1) * 64);
            #pragma unroll
            for (int i = 0; i < 6; ++i)
                breg[i] = *reinterpret_cast<const u32x4*>(bgp[i] + (ks + 1) * 64);
        }
        bf16x8 af0 = *reinterpret_cast<const bf16x8*>(&sA[cur][aswz0]);
        bf16x8 af1 = *reinterpret_cast<const bf16x8*>(&sA[cur][aswz1]);
        #pragma unroll
        for (int j = 0; j < 3; ++j) {
            bf16x8 b0 = *reinterpret_cast<const bf16x8*>(&sB[cur][bswz0[j]]);
            bf16x8 b1 = *reinterpret_cast<const bf16x8*>(&sB[cur][bswz1[j]]);
            acc[j] = __builtin_amdgcn_mfma_f32_16x16x32_bf16(b0, af0, acc[j], 0, 0, 0);
            acc[j] = __builtin_amdgcn_mfma_f32_16x16x32_bf16(b1, af1, acc[j], 0, 0, 0);
        }
        if (ks < 15) {
            uint2 aw; aw.x = cvtpk(areg.x, areg.y); aw.y = cvtpk(areg.z, areg.w);
            *reinterpret_cast<uint2*>(&sA[cur ^ 1][aoff]) = aw;
            #pragma unroll
            for (int i = 0; i < 6; ++i)
                *reinterpret_cast<u32x4*>(&sB[cur ^ 1][boff[i]]) = breg[i];
        }
        __syncthreads();
    }

    const int row = m0 + l16;
    #pragma unroll
    for (int j = 0; j < 3; ++j) {
        const int nt = w * 3 + j;
        const int nb = nt * 16 + 4 * lq;
        if (nt < 4) {
            const int tq = row >> 5, lr = row & 31;
            const int kc = nb >> 4, hi2 = (nb >> 3) & 1, jj = nb & 7;
            short4 qs;
            qs.x = f2bf(acc[j][0] * 0.18033688011112042f);
            qs.y = f2bf(acc[j][1] * 0.18033688011112042f);
            qs.z = f2bf(acc[j][2] * 0.18033688011112042f);
            qs.w = f2bf(acc[j][3] * 0.18033688011112042f);
            *reinterpret_cast<short4*>(Qf + ((size_t)(tq * 4 + kc) * 64 + lr + 32 * hi2) * 8 + jj) = qs;
        } else if (nt < 8) {
            const int col = nb - 64;
            const int c = row >> 6, rr = row & 63, hk = rr >> 5, lr = rr & 31;
            const int kc = col >> 4, hi2 = (col >> 3) & 1, jj = col & 7;
            short4 ks4;
            ks4.x = f2bf(acc[j][0]); ks4.y = f2bf(acc[j][1]);
            ks4.z = f2bf(acc[j][2]); ks4.w = f2bf(acc[j][3]);
            *reinterpret_cast<short4*>(Kf + ((size_t)(c * 8 + 4 * hk + kc) * 64 + lr + 32 * hi2) * 8 + jj) = ks4;
        } else {
            #pragma unroll
            for (int r = 0; r < 4; ++r)
                sV[nb + r - 128][l16] = __float2bfloat16(acc[j][r]);
        }
    }
    __syncthreads();
    // V fragment store: 64 d x 16 rows, thread covers 4 rows of one d
    const int vd = tid >> 2, vm = (tid & 3) * 4;
    short4 vv = *reinterpret_cast<const short4*>(&sV[vd][vm]);
    const int kv = m0 + vm;
    const int c = kv >> 6, ks2 = (kv >> 4) & 3, hi2 = (kv >> 3) & 1, jj = kv & 7;
    *reinterpret_cast<short4*>(Vf + ((size_t)(c * 8 + 4 * (vd >> 5) + ks2) * 64 + (vd & 31) + 32 * hi2) * 8 + jj) = vv;
}

// ---------------- kernel 2: causal flash attention -----------------
// 4-WAVE blocks + launch_bounds(256,3): VGPR cap 168 lets the K/V
// prefetch live ranges survive (8-wave blocks force either <=128 VGPR,
// killing the pipeline, or 1 block/CU). 3 blocks/CU = 12 waves/CU.
// grid 1024 = 128 pairs x 8 splits; block (p = bid>>3, s = bid&7) does
// tiles p and 255-p. slot = w*8+s in [0,32); chunks c = slot + 32*i.
// FIXED-MAX softmax (S pre-biased -16, base-2); plain-sum merges.
__global__ __launch_bounds__(256, 3) void attn_kernel(
    const __hip_bfloat16* __restrict__ Qf,
    const __hip_bfloat16* __restrict__ Kf,
    const __hip_bfloat16* __restrict__ Vf,
    float* __restrict__ Part) {  // [256 tiles][8 splits][PREC] f32
    __shared__ __hip_bfloat16 sO[4][64][32];
    __shared__ float sL[4][32];
    const int tid = threadIdx.x;
    const int w = tid >> 6, lane = tid & 63;
    const int l31 = lane & 31, hi = lane >> 5;
    const int p = blockIdx.x >> 3, s = blockIdx.x & 7;
    const int slot = w * 8 + s;

    for (int ti = 0; ti < 2; ++ti) {
        const int t = ti ? (255 - p) : p;
        const int q0 = t * 32;
        const int Ct = (q0 + 95) >> 6;   // ceil((q0+32)/64)
        const int qabs = q0 + l31;

        bf16x8 qf[4];
        #pragma unroll
        for (int kc = 0; kc < 4; ++kc)
            qf[kc] = *reinterpret_cast<const bf16x8*>(
                Qf + ((size_t)(t * 4 + kc) * 64 + lane) * 8);

        float l = 0.f;
        f32x16 Oa = (f32x16)0.f, Oc = (f32x16)0.f;

        if (slot < Ct) {
            bf16x8 ka[4], kb2[4], va[4], vb[4];
            {
                const __hip_bfloat16* kp = Kf + (size_t)slot * 4096 + lane * 8;
                const __hip_bfloat16* vp = Vf + (size_t)slot * 4096 + lane * 8;
                #pragma unroll
                for (int kc = 0; kc < 4; ++kc) {
                    ka[kc]  = *reinterpret_cast<const bf16x8*>(kp + kc * 512);
                    kb2[kc] = *reinterpret_cast<const bf16x8*>(kp + 2048 + kc * 512);
                    va[kc]  = *reinterpret_cast<const bf16x8*>(vp + kc * 512);
                    vb[kc]  = *reinterpret_cast<const bf16x8*>(vp + 2048 + kc * 512);
                }
            }

            for (int c = slot; c < Ct; c += 32) {
                const int kv0 = c * 64;
                const bool more = (c + 32) < Ct;

                // S accumulators pre-biased to -16: P = exp2(S) directly
                f32x16 Sa = (f32x16)(-16.f), Sb = (f32x16)(-16.f);
                #pragma unroll
                for (int kc = 0; kc < 4; ++kc)
                    Sa = __builtin_amdgcn_mfma_f32_32x32x16_bf16(ka[kc], qf[kc], Sa, 0, 0, 0);
                #pragma unroll
                for (int kc = 0; kc < 4; ++kc)
                    Sb = __builtin_amdgcn_mfma_f32_32x32x16_bf16(kb2[kc], qf[kc], Sb, 0, 0, 0);

                if (more) {  // prefetch K(c+32), coalesced 1KB loads
                    const __hip_bfloat16* kn = Kf + (size_t)(c + 32) * 4096 + lane * 8;
                    #pragma unroll
                    for (int kc = 0; kc < 4; ++kc) {
                        ka[kc]  = *reinterpret_cast<const bf16x8*>(kn + kc * 512);
                        kb2[kc] = *reinterpret_cast<const bf16x8*>(kn + 2048 + kc * 512);
                    }
                }

                if (kv0 + 64 > q0) {  // only near-diagonal chunks need masking
                    #pragma unroll
                    for (int r = 0; r < 16; ++r) {
                        const int rowk = (r & 3) + 8 * (r >> 2) + 4 * hi;
                        if (kv0 + rowk > qabs)      Sa[r] = -1.0e30f;
                        if (kv0 + 32 + rowk > qabs) Sb[r] = -1.0e30f;
                    }
                }

                #pragma unroll
                for (int r = 0; r < 16; ++r) Sa[r] = exp2f(Sa[r]);
                #pragma unroll
                for (int r = 0; r < 16; ++r) Sb[r] = exp2f(Sb[r]);
                float s8[8];
                #pragma unroll
                for (int j = 0; j < 8; ++j)
                    s8[j] = (Sa[2*j] + Sa[2*j+1]) + (Sb[2*j] + Sb[2*j+1]);
                #pragma unroll
                for (int j = 0; j < 4; ++j) s8[j] += s8[j+4];
                float ps = (s8[0] + s8[2]) + (s8[1] + s8[3]);
                ps += __shfl_xor(ps, 32);
                l += ps;

                // P^T -> bf16 B-fragments via cvt_pk + permlane32_swap (T12)
                bf16x8 F0, F1, F2, F3;
                {
                    unsigned a0 = cvtpk(Sa[0], Sa[1]),  a1 = cvtpk(Sa[2], Sa[3]);
                    unsigned a2 = cvtpk(Sa[4], Sa[5]),  a3 = cvtpk(Sa[6], Sa[7]);
                    plswap(a0, a2); plswap(a1, a3);
                    u32x4 w0; w0[0]=a0; w0[1]=a1; w0[2]=a2; w0[3]=a3;
                    F0 = __builtin_bit_cast(bf16x8, w0);
                    unsigned b0 = cvtpk(Sa[8], Sa[9]),  b1 = cvtpk(Sa[10], Sa[11]);
                    unsigned b2 = cvtpk(Sa[12], Sa[13]), b3 = cvtpk(Sa[14], Sa[15]);
                    plswap(b0, b2); plswap(b1, b3);
                    u32x4 w1; w1[0]=b0; w1[1]=b1; w1[2]=b2; w1[3]=b3;
                    F1 = __builtin_bit_cast(bf16x8, w1);
                    unsigned c0_ = cvtpk(Sb[0], Sb[1]),  c1_ = cvtpk(Sb[2], Sb[3]);
                    unsigned c2_ = cvtpk(Sb[4], Sb[5]),  c3_ = cvtpk(Sb[6], Sb[7]);
                    plswap(c0_, c2_); plswap(c1_, c3_);
                    u32x4 w2; w2[0]=c0_; w2[1]=c1_; w2[2]=c2_; w2[3]=c3_;
                    F2 = __builtin_bit_cast(bf16x8, w2);
                    unsigned d0 = cvtpk(Sb[8], Sb[9]),  d1 = cvtpk(Sb[10], Sb[11]);
                    unsigned d2 = cvtpk(Sb[12], Sb[13]), d3 = cvtpk(Sb[14], Sb[15]);
                    plswap(d0, d2); plswap(d1, d3);
                    u32x4 w3; w3[0]=d0; w3[1]=d1; w3[2]=d2; w3[3]=d3;
                    F3 = __builtin_bit_cast(bf16x8, w3);
                }
                bf16x8 Fa[4] = {F0, F1, F2, F3};
                #pragma unroll
                for (int ks = 0; ks < 4; ++ks) {
                    Oa = __builtin_amdgcn_mfma_f32_32x32x16_bf16(va[ks], Fa[ks], Oa, 0, 0, 0);
                    Oc = __builtin_amdgcn_mfma_f32_32x32x16_bf16(vb[ks], Fa[ks], Oc, 0, 0, 0);
                }

                if (more) {  // prefetch V(c+32)
                    const __hip_bfloat16* vn = Vf + (size_t)(c + 32) * 4096 + lane * 8;
                    #pragma unroll
                    for (int ks = 0; ks < 4; ++ks) {
                        va[ks] = *reinterpret_cast<const bf16x8*>(vn + ks * 512);
                        vb[ks] = *reinterpret_cast<const bf16x8*>(vn + 2048 + ks * 512);
                    }
                }
            }
        }

        if (hi == 0) sL[w][l31] = l;
        #pragma unroll
        for (int r = 0; r < 16; ++r) {
            const int d = (r & 3) + 8 * (r >> 2) + 4 * hi;
            sO[w][d][l31]      = __float2bfloat16(Oa[r]);
            sO[w][d + 32][l31] = __float2bfloat16(Oc[r]);
        }
        __syncthreads();

        // plain-sum merge of the 4 wave partials (shared fixed max)
        float* pb = Part + (size_t)(t * 8 + s) * PREC;
        for (int e = tid; e < 2048; e += 256) {
            const int d = e >> 5, qq = e & 31;
            float ob = 0.f;
            #pragma unroll
            for (int wi = 0; wi < 4; ++wi) ob += __bfloat162float(sO[wi][d][qq]);
            pb[e] = ob;
            if (d == 0) {
                float lb = 0.f;
                #pragma unroll
                for (int wi = 0; wi < 4; ++wi) lb += sL[wi][qq];
                pb[2048 + qq] = lb;
            }
        }
        __syncthreads();
    }
}

// ---------------- kernel 2b: merge the 8 kv-split partials ---------
__global__ __launch_bounds__(256) void merge_kernel(
    const float* __restrict__ Part, __hip_bfloat16* __restrict__ Ob) {
    const int t = blockIdx.x, q0 = t * 32;
    const float* pp = Part + (size_t)(t * 8) * PREC;
    for (int e = threadIdx.x; e < 2048; e += 256) {
        const int qq = e & 31, d = e >> 5;
        float ll = 0.f, oo = 0.f;
        #pragma unroll
        for (int si = 0; si < 8; ++si) {
            ll += pp[si * PREC + 2048 + qq];
            oo += pp[si * PREC + d * 32 + qq];
        }
        Ob[(size_t)(q0 + qq) * 64 + d] = __float2bfloat16(oo / ll);
    }
}

// ---------------- kernel 3: out = O @ Wout + bout ------------------
__global__ __launch_bounds__(256) void out_kernel(
    const __hip_bfloat16* __restrict__ Ob,
    const __hip_bfloat16* __restrict__ WoT,
    const float* __restrict__ bout,
    float* __restrict__ out) {
    const int tid = threadIdx.x;
    const int w = tid >> 6, lane = tid & 63;
    const int l16 = lane & 15, lq = lane >> 4;
    const int m0 = blockIdx.x * 64 + w * 16;
    const int n0 = blockIdx.y * 256;

    const __hip_bfloat16* orow = Ob + (size_t)(m0 + l16) * 64;
    bf16x8 a0 = *reinterpret_cast<const bf16x8*>(orow + 8 * lq);
    bf16x8 a1 = *reinterpret_cast<const bf16x8*>(orow + 32 + 8 * lq);

    const int row = m0 + l16;
    for (int nt = 0; nt < 16; ++nt) {
        const __hip_bfloat16* wrow = WoT + (size_t)(n0 + nt * 16 + l16) * 64;
        bf16x8 b0 = *reinterpret_cast<const bf16x8*>(wrow + 8 * lq);
        bf16x8 b1 = *reinterpret_cast<const bf16x8*>(wrow + 32 + 8 * lq);
        f32x4 acc = (f32x4)0.f;
        acc = __builtin_amdgcn_mfma_f32_16x16x32_bf16(b0, a0, acc, 0, 0, 0);
        acc = __builtin_amdgcn_mfma_f32_16x16x32_bf16(b1, a1, acc, 0, 0, 0);
        const int nb = n0 + nt * 16 + 4 * lq;
        float4 bb = *reinterpret_cast<const float4*>(bout + nb);
        float4 res;
        res.x = acc[0] + bb.x; res.y = acc[1] + bb.y;
        res.z = acc[2] + bb.z; res.w = acc[3] + bb.w;
        *reinterpret_cast<float4*>(out + (size_t)row * 1024 + nb) = res;
    }
}

// ---------------- launch -------------------------------------------
extern "C" void kernel_launch(void* const* d_in, const int* in_sizes, int n_in,
                              void* d_out, int out_size, void* d_ws, size_t ws_size,
                              hipStream_t stream) {
    const float* x    = (const float*)d_in[0];
    const float* Wqkv = (const float*)d_in[1];
    const float* Wout = (const float*)d_in[2];
    const float* bout = (const float*)d_in[3];
    float* out = (float*)d_out;

    char* ws = (char*)d_ws;
    __hip_bfloat16* Wt  = (__hip_bfloat16*)(ws);                 // 393216 B
    __hip_bfloat16* WoT = (__hip_bfloat16*)(ws + 393216);        // 131072 B
    __hip_bfloat16* Qf  = (__hip_bfloat16*)(ws + 524288);        // 1 MiB
    __hip_bfloat16* Kf  = (__hip_bfloat16*)(ws + 1572864);       // 1 MiB
    __hip_bfloat16* Vf  = (__hip_bfloat16*)(ws + 2621440);       // 1 MiB
    __hip_bfloat16* Ob  = (__hip_bfloat16*)(ws + 3670016);       // 1 MiB
    float*          Part = (float*)(ws + 4718592);               // 17.04 MB

    conv_kernel<<<256, 256, 0, stream>>>(Wqkv, Wout, Wt, WoT);
    qkv_kernel<<<512, 256, 0, stream>>>(x, Wt, Qf, Kf, Vf);
    attn_kernel<<<1024, 256, 0, stream>>>(Qf, Kf, Vf, Part);
    merge_kernel<<<256, 256, 0, stream>>>(Part, Ob);
    out_kernel<<<dim3(128, 4), 256, 0, stream>>>(Ob, WoT, bout, out);
}

// Round 18
// 69.684 us; speedup vs baseline: 1.2021x; 1.2021x over previous
//
#include <hip/hip_runtime.h>
#include <hip/hip_bf16.h>

#define N_TOK 8192
#define RREC 4352   // bytes/record: 4096 bf16-O (d-major [64][32]) + 128 f32-l + pad

typedef float f32x4  __attribute__((ext_vector_type(4)));
typedef float f32x16 __attribute__((ext_vector_type(16)));
typedef short bf16x8 __attribute__((ext_vector_type(8)));
typedef unsigned int u32x4 __attribute__((ext_vector_type(4)));

__device__ inline short f2bf(float f) {
    union { __hip_bfloat16 h; short s; } u;
    u.h = __float2bfloat16(f);
    return u.s;
}
__device__ inline unsigned cvtpk(float lo, float hi) {
    unsigned r;
    asm("v_cvt_pk_bf16_f32 %0, %1, %2" : "=v"(r) : "v"(lo), "v"(hi));
    return r;
}
__device__ inline void plswap(unsigned &a, unsigned &b) {
    asm("v_permlane32_swap_b32 %0, %1" : "+v"(a), "+v"(b));
}
// async global->LDS, 16B per lane; LDS dest = wave-uniform base + lane*16
__device__ inline void gload_lds16(const __hip_bfloat16* g, __hip_bfloat16* s) {
    __builtin_amdgcn_global_load_lds(
        (const __attribute__((address_space(1))) void*)(g),
        (__attribute__((address_space(3))) void*)(s), 16, 0, 0);
}

// Fragment-major tensor layouts (all 1 MiB):
//  Qf[((t*4 + kc)*64 + lane)*8 + j]      : Q[t*32 + (lane&31)][kc*16 + 8*(lane>>5) + j]
//  Kf[((c*8 + 4*hk + kc)*64 + lane)*8+j] : K[c*64 + 32*hk + (lane&31)][kc*16 + 8*(lane>>5) + j]
//  Vf[((c*8 + 4*hd + ks)*64 + lane)*8+j] : V[c*64 + ks*16 + 8*(lane>>5) + j][32*hd + (lane&31)]

// ---------------- kernel 0: weight convert/transpose (LDS tiled) ----
__global__ __launch_bounds__(256) void conv_kernel(
    const float* __restrict__ Wqkv,
    const float* __restrict__ Wout,
    __hip_bfloat16* __restrict__ Wt,      // [192][1024]
    __hip_bfloat16* __restrict__ WoT) {   // [1024][64]
    __shared__ float tile[32][33];
    const int t = threadIdx.x;
    const int cc = t & 31, rbase = t >> 5;
    const int b = blockIdx.x;
    if (b < 192) {
        const int r0 = (b & 31) * 32;   // k
        const int c0 = (b >> 5) * 32;   // n
        #pragma unroll
        for (int it = 0; it < 4; ++it) {
            const int rr = rbase + it * 8;
            tile[rr][cc] = Wqkv[(size_t)(r0 + rr) * 192 + c0 + cc];
        }
        __syncthreads();
        #pragma unroll
        for (int it = 0; it < 4; ++it) {
            const int rr = rbase + it * 8;
            Wt[(size_t)(c0 + rr) * 1024 + r0 + cc] = __float2bfloat16(tile[cc][rr]);
        }
    } else {
        const int bb = b - 192;
        const int r0 = (bb & 1) * 32;   // k (rows of Wout)
        const int c0 = (bb >> 1) * 32;  // n
        #pragma unroll
        for (int it = 0; it < 4; ++it) {
            const int rr = rbase + it * 8;
            tile[rr][cc] = Wout[(size_t)(r0 + rr) * 1024 + c0 + cc];
        }
        __syncthreads();
        #pragma unroll
        for (int it = 0; it < 4; ++it) {
            const int rr = rbase + it * 8;
            WoT[(size_t)(c0 + rr) * 64 + r0 + cc] = __float2bfloat16(tile[cc][rr]);
        }
    }
}

// ---------------- kernel 1: qkv = x @ Wqkv -------------------------
// LDS-staged double-buffered GEMM. BM=16, BN=192, BK=64, grid 512,
// 256 thr (4 waves) -> 2 independent blocks/CU (barrier overlap).
// Epilogue writes Qf/Kf/Vf in MFMA-fragment-major layout.
__global__ __launch_bounds__(256) void qkv_kernel(
    const float* __restrict__ x,
    const __hip_bfloat16* __restrict__ Wt,   // [192][1024]
    __hip_bfloat16* __restrict__ Qf,
    __hip_bfloat16* __restrict__ Kf,
    __hip_bfloat16* __restrict__ Vf) {
    __shared__ __hip_bfloat16 sA[2][16 * 64];
    __shared__ __hip_bfloat16 sB[2][192 * 64];
    __shared__ __hip_bfloat16 sV[64][20];
    const int tid = threadIdx.x;
    const int w = tid >> 6, lane = tid & 63;
    const int l16 = lane & 15, lq = lane >> 4;
    const int m0 = blockIdx.x * 16;

    const int ar = tid >> 4;
    const int ac = (tid & 15) >> 1;
    const int ah = tid & 1;
    const float* agp = x + (size_t)(m0 + ar) * 1024 + ac * 8 + ah * 4;
    const int aoff = ar * 64 + ((ac ^ (ar & 7)) * 8) + ah * 4;

    int boff[6];
    const __hip_bfloat16* bgp[6];
    #pragma unroll
    for (int i = 0; i < 6; ++i) {
        const int q = i * 256 + tid;
        const int r = q >> 3, c = q & 7;
        bgp[i] = Wt + (size_t)r * 1024 + c * 8;
        boff[i] = r * 64 + ((c ^ (r & 7)) * 8);
    }

    const int arow = l16;
    const int aswz0 = arow * 64 + ((lq ^ (arow & 7)) * 8);
    const int aswz1 = arow * 64 + (((4 + lq) ^ (arow & 7)) * 8);
    int bswz0[3], bswz1[3];
    #pragma unroll
    for (int j = 0; j < 3; ++j) {
        const int row = (w * 3 + j) * 16 + l16;
        bswz0[j] = row * 64 + ((lq ^ (row & 7)) * 8);
        bswz1[j] = row * 64 + (((4 + lq) ^ (row & 7)) * 8);
    }

    f32x4 acc[3];
    #pragma unroll
    for (int j = 0; j < 3; ++j) acc[j] = (f32x4)0.f;

    float4 areg;
    u32x4 breg[6];

    areg = *reinterpret_cast<const float4*>(agp);
    #pragma unroll
    for (int i = 0; i < 6; ++i)
        breg[i] = *reinterpret_cast<const u32x4*>(bgp[i]);
    {
        uint2 aw; aw.x = cvtpk(areg.x, areg.y); aw.y = cvtpk(areg.z, areg.w);
        *reinterpret_cast<uint2*>(&sA[0][aoff]) = aw;
        #pragma unroll
        for (int i = 0; i < 6; ++i)
            *reinterpret_cast<u32x4*>(&sB[0][boff[i]]) = breg[i];
    }
    __syncthreads();

    for (int ks = 0; ks < 16; ++ks) {
        const int cur = ks & 1;
        if (ks < 15) {
            areg = *reinterpret_cast<const float4*>(agp + (ks + 1) * 64);
            #pragma unroll
            for (int i = 0; i < 6; ++i)
                breg[i] = *reinterpret_cast<const u32x4*>(bgp[i] + (ks + 1) * 64);
        }
        bf16x8 af0 = *reinterpret_cast<const bf16x8*>(&sA[cur][aswz0]);
        bf16x8 af1 = *reinterpret_cast<const bf16x8*>(&sA[cur][aswz1]);
        #pragma unroll
        for (int j = 0; j < 3; ++j) {
            bf16x8 b0 = *reinterpret_cast<const bf16x8*>(&sB[cur][bswz0[j]]);
            bf16x8 b1 = *reinterpret_cast<const bf16x8*>(&sB[cur][bswz1[j]]);
            acc[j] = __builtin_amdgcn_mfma_f32_16x16x32_bf16(b0, af0, acc[j], 0, 0, 0);
            acc[j] = __builtin_amdgcn_mfma_f32_16x16x32_bf16(b1, af1, acc[j], 0, 0, 0);
        }
        if (ks < 15) {
            uint2 aw; aw.x = cvtpk(areg.x, areg.y); aw.y = cvtpk(areg.z, areg.w);
            *reinterpret_cast<uint2*>(&sA[cur ^ 1][aoff]) = aw;
            #pragma unroll
            for (int i = 0; i < 6; ++i)
                *reinterpret_cast<u32x4*>(&sB[cur ^ 1][boff[i]]) = breg[i];
        }
        __syncthreads();
    }

    const int row = m0 + l16;
    #pragma unroll
    for (int j = 0; j < 3; ++j) {
        const int nt = w * 3 + j;
        const int nb = nt * 16 + 4 * lq;
        if (nt < 4) {
            const int tq = row >> 5, lr = row & 31;
            const int kc = nb >> 4, hi2 = (nb >> 3) & 1, jj = nb & 7;
            short4 qs;
            qs.x = f2bf(acc[j][0] * 0.18033688011112042f);
            qs.y = f2bf(acc[j][1] * 0.18033688011112042f);
            qs.z = f2bf(acc[j][2] * 0.18033688011112042f);
            qs.w = f2bf(acc[j][3] * 0.18033688011112042f);
            *reinterpret_cast<short4*>(Qf + ((size_t)(tq * 4 + kc) * 64 + lr + 32 * hi2) * 8 + jj) = qs;
        } else if (nt < 8) {
            const int col = nb - 64;
            const int c = row >> 6, rr = row & 63, hk = rr >> 5, lr = rr & 31;
            const int kc = col >> 4, hi2 = (col >> 3) & 1, jj = col & 7;
            short4 ks4;
            ks4.x = f2bf(acc[j][0]); ks4.y = f2bf(acc[j][1]);
            ks4.z = f2bf(acc[j][2]); ks4.w = f2bf(acc[j][3]);
            *reinterpret_cast<short4*>(Kf + ((size_t)(c * 8 + 4 * hk + kc) * 64 + lr + 32 * hi2) * 8 + jj) = ks4;
        } else {
            #pragma unroll
            for (int r = 0; r < 4; ++r)
                sV[nb + r - 128][l16] = __float2bfloat16(acc[j][r]);
        }
    }
    __syncthreads();
    const int vd = tid >> 2, vm = (tid & 3) * 4;
    short4 vv = *reinterpret_cast<const short4*>(&sV[vd][vm]);
    const int kv = m0 + vm;
    const int c = kv >> 6, ks2 = (kv >> 4) & 3, hi2 = (kv >> 3) & 1, jj = kv & 7;
    *reinterpret_cast<short4*>(Vf + ((size_t)(c * 8 + 4 * (vd >> 5) + ks2) * 64 + (vd & 31) + 32 * hi2) * 8 + jj) = vv;
}

// ---------------- kernel 2: causal flash attention (glds-staged) ---
// Block = 512 thr / 8 waves covering 4 q-tiles: wave w -> tile
// tq = qb*4 + (w>>1), kv-half h = w&1. Grid 512 = 64 qb x 8 splits,
// snake-ordered (desc then asc qb) so big+small blocks pair per CU.
// Per stage: all waves glds-stage next chunk's K+V (16KB) into buf^1
// (un-sinkable async, drained by the stage-end barrier), compute the
// current chunk FROM LDS. K/V L2 traffic /8. FIXED-MAX softmax.
// Each wave writes its own bf16-normalized partial record (tq, s*2+h).
__global__ __launch_bounds__(512, 4) void attn_kernel(
    const __hip_bfloat16* __restrict__ Qf,
    const __hip_bfloat16* __restrict__ Kf,
    const __hip_bfloat16* __restrict__ Vf,
    char* __restrict__ Part) {  // [256 tiles][16 recs][RREC]
    __shared__ __hip_bfloat16 sK[2][4096];
    __shared__ __hip_bfloat16 sV2[2][4096];
    const int tid = threadIdx.x;
    const int w = tid >> 6, lane = tid & 63;
    const int l31 = lane & 31, hi = lane >> 5;
    const int bid = blockIdx.x;
    const int qb = (bid < 256) ? (63 - (bid >> 3)) : ((bid - 256) >> 3);
    const int s = bid & 7;
    const int tsub = w >> 1, h = w & 1;
    const int tq = qb * 4 + tsub;
    const int q0 = tq * 32;
    const int qabs = q0 + l31;
    const int CtB = 2 * qb + 2;                       // block chunk count
    const int nst = (CtB > s) ? ((CtB - s + 7) >> 3) : 0;

    bf16x8 qf[4];
    #pragma unroll
    for (int kc = 0; kc < 4; ++kc)
        qf[kc] = *reinterpret_cast<const bf16x8*>(
            Qf + ((size_t)(tq * 4 + kc) * 64 + lane) * 8);

    float l = 0.f;
    f32x16 Oa = (f32x16)0.f, Oc = (f32x16)0.f;

    const size_t gofs = (size_t)w * 512 + lane * 8;   // element offset in chunk

    if (nst > 0) gload_lds16(Kf + (size_t)s * 4096 + gofs, &sK[0][w * 512]),
                 gload_lds16(Vf + (size_t)s * 4096 + gofs, &sV2[0][w * 512]);
    __syncthreads();

    int cur = 0;
    for (int st = 0; st < nst; ++st) {
        const int c = s + st * 8;
        if (st + 1 < nst) {   // stage next chunk into the other buffer
            gload_lds16(Kf + (size_t)(c + 8) * 4096 + gofs, &sK[cur ^ 1][w * 512]);
            gload_lds16(Vf + (size_t)(c + 8) * 4096 + gofs, &sV2[cur ^ 1][w * 512]);
        }

        const int kv0h = c * 64 + h * 32;
        if (kv0h <= q0 + 31) {   // this wave-half has unmasked work
            f32x16 Sa = (f32x16)(-16.f);   // pre-biased: P = exp2(S)
            #pragma unroll
            for (int kc = 0; kc < 4; ++kc) {
                bf16x8 ka = *reinterpret_cast<const bf16x8*>(
                    &sK[cur][((4 * h + kc) * 64 + lane) * 8]);
                Sa = __builtin_amdgcn_mfma_f32_32x32x16_bf16(ka, qf[kc], Sa, 0, 0, 0);
            }

            if (kv0h + 32 > q0) {   // near-diagonal masking
                #pragma unroll
                for (int r = 0; r < 16; ++r) {
                    const int rowk = (r & 3) + 8 * (r >> 2) + 4 * hi;
                    if (kv0h + rowk > qabs) Sa[r] = -1.0e30f;
                }
            }

            #pragma unroll
            for (int r = 0; r < 16; ++r) Sa[r] = exp2f(Sa[r]);
            float s8[8];
            #pragma unroll
            for (int j = 0; j < 8; ++j) s8[j] = Sa[2 * j] + Sa[2 * j + 1];
            #pragma unroll
            for (int j = 0; j < 4; ++j) s8[j] += s8[j + 4];
            float ps = (s8[0] + s8[2]) + (s8[1] + s8[3]);
            ps += __shfl_xor(ps, 32);
            l += ps;

            // P^T -> bf16 B-fragments via cvt_pk + permlane32_swap (T12)
            bf16x8 F0, F1;
            {
                unsigned a0 = cvtpk(Sa[0], Sa[1]),  a1 = cvtpk(Sa[2], Sa[3]);
                unsigned a2 = cvtpk(Sa[4], Sa[5]),  a3 = cvtpk(Sa[6], Sa[7]);
                plswap(a0, a2); plswap(a1, a3);
                u32x4 w0; w0[0] = a0; w0[1] = a1; w0[2] = a2; w0[3] = a3;
                F0 = __builtin_bit_cast(bf16x8, w0);
                unsigned b0 = cvtpk(Sa[8], Sa[9]),  b1 = cvtpk(Sa[10], Sa[11]);
                unsigned b2 = cvtpk(Sa[12], Sa[13]), b3 = cvtpk(Sa[14], Sa[15]);
                plswap(b0, b2); plswap(b1, b3);
                u32x4 w1; w1[0] = b0; w1[1] = b1; w1[2] = b2; w1[3] = b3;
                F1 = __builtin_bit_cast(bf16x8, w1);
            }
            // PV: global kv-subchunk ks = 2h + {0,1}; both d-halves
            #pragma unroll
            for (int ks = 0; ks < 2; ++ks) {
                bf16x8 Fk = ks ? F1 : F0;
                bf16x8 v0 = *reinterpret_cast<const bf16x8*>(
                    &sV2[cur][((2 * h + ks) * 64 + lane) * 8]);
                bf16x8 v1 = *reinterpret_cast<const bf16x8*>(
                    &sV2[cur][((4 + 2 * h + ks) * 64 + lane) * 8]);
                Oa = __builtin_amdgcn_mfma_f32_32x32x16_bf16(v0, Fk, Oa, 0, 0, 0);
                Oc = __builtin_amdgcn_mfma_f32_32x32x16_bf16(v1, Fk, Oc, 0, 0, 0);
            }
        }

        __syncthreads();   // drains vmcnt (next buf staged) + read fence
        cur ^= 1;
    }

    // epilogue: bf16-normalized partial record (zeros if idle)
    char* rec = Part + ((size_t)tq * 16 + s * 2 + h) * RREC;
    __hip_bfloat16* On = (__hip_bfloat16*)rec;
    const float invl = (l > 0.f) ? (1.0f / l) : 0.f;
    #pragma unroll
    for (int r = 0; r < 16; ++r) {
        const int d = (r & 3) + 8 * (r >> 2) + 4 * hi;
        On[d * 32 + l31]        = __float2bfloat16(Oa[r] * invl);
        On[(d + 32) * 32 + l31] = __float2bfloat16(Oc[r] * invl);
    }
    if (hi == 0) ((float*)(rec + 4096))[l31] = l;
}

// ---------------- kernel 2b: merge the 16 partial records ----------
__global__ __launch_bounds__(256) void merge_kernel(
    const char* __restrict__ Part, __hip_bfloat16* __restrict__ Ob) {
    const int t = blockIdx.x, q0 = t * 32;
    const char* base = Part + (size_t)t * 16 * RREC;
    for (int e = threadIdx.x; e < 2048; e += 256) {
        const int qq = e & 31, d = e >> 5;
        float ll = 0.f, oo = 0.f;
        #pragma unroll
        for (int rid = 0; rid < 16; ++rid) {
            const char* rec = base + rid * RREC;
            const float ls = ((const float*)(rec + 4096))[qq];
            ll += ls;
            oo += ls * __bfloat162float(((const __hip_bfloat16*)rec)[d * 32 + qq]);
        }
        Ob[(size_t)(q0 + qq) * 64 + d] = __float2bfloat16(oo / ll);
    }
}

// ---------------- kernel 3: out = O @ Wout + bout ------------------
__global__ __launch_bounds__(256) void out_kernel(
    const __hip_bfloat16* __restrict__ Ob,
    const __hip_bfloat16* __restrict__ WoT,
    const float* __restrict__ bout,
    float* __restrict__ out) {
    const int tid = threadIdx.x;
    const int w = tid >> 6, lane = tid & 63;
    const int l16 = lane & 15, lq = lane >> 4;
    const int m0 = blockIdx.x * 64 + w * 16;
    const int n0 = blockIdx.y * 256;

    const __hip_bfloat16* orow = Ob + (size_t)(m0 + l16) * 64;
    bf16x8 a0 = *reinterpret_cast<const bf16x8*>(orow + 8 * lq);
    bf16x8 a1 = *reinterpret_cast<const bf16x8*>(orow + 32 + 8 * lq);

    const int row = m0 + l16;
    for (int nt = 0; nt < 16; ++nt) {
        const __hip_bfloat16* wrow = WoT + (size_t)(n0 + nt * 16 + l16) * 64;
        bf16x8 b0 = *reinterpret_cast<const bf16x8*>(wrow + 8 * lq);
        bf16x8 b1 = *reinterpret_cast<const bf16x8*>(wrow + 32 + 8 * lq);
        f32x4 acc = (f32x4)0.f;
        acc = __builtin_amdgcn_mfma_f32_16x16x32_bf16(b0, a0, acc, 0, 0, 0);
        acc = __builtin_amdgcn_mfma_f32_16x16x32_bf16(b1, a1, acc, 0, 0, 0);
        const int nb = n0 + nt * 16 + 4 * lq;
        float4 bb = *reinterpret_cast<const float4*>(bout + nb);
        float4 res;
        res.x = acc[0] + bb.x; res.y = acc[1] + bb.y;
        res.z = acc[2] + bb.z; res.w = acc[3] + bb.w;
        *reinterpret_cast<float4*>(out + (size_t)row * 1024 + nb) = res;
    }
}

// ---------------- launch -------------------------------------------
extern "C" void kernel_launch(void* const* d_in, const int* in_sizes, int n_in,
                              void* d_out, int out_size, void* d_ws, size_t ws_size,
                              hipStream_t stream) {
    const float* x    = (const float*)d_in[0];
    const float* Wqkv = (const float*)d_in[1];
    const float* Wout = (const float*)d_in[2];
    const float* bout = (const float*)d_in[3];
    float* out = (float*)d_out;

    char* ws = (char*)d_ws;
    __hip_bfloat16* Wt  = (__hip_bfloat16*)(ws);                 // 393216 B
    __hip_bfloat16* WoT = (__hip_bfloat16*)(ws + 393216);        // 131072 B
    __hip_bfloat16* Qf  = (__hip_bfloat16*)(ws + 524288);        // 1 MiB
    __hip_bfloat16* Kf  = (__hip_bfloat16*)(ws + 1572864);       // 1 MiB
    __hip_bfloat16* Vf  = (__hip_bfloat16*)(ws + 2621440);       // 1 MiB
    __hip_bfloat16* Ob  = (__hip_bfloat16*)(ws + 3670016);       // 1 MiB
    char*           Part = ws + 4718592;                         // 256*16*4352 = 17.8 MB

    conv_kernel<<<256, 256, 0, stream>>>(Wqkv, Wout, Wt, WoT);
    qkv_kernel<<<512, 256, 0, stream>>>(x, Wt, Qf, Kf, Vf);
    attn_kernel<<<512, 512, 0, stream>>>(Qf, Kf, Vf, Part);
    merge_kernel<<<256, 256, 0, stream>>>(Part, Ob);
    out_kernel<<<dim3(128, 4), 256, 0, stream>>>(Ob, WoT, bout, out);
}

// Round 19
// 66.112 us; speedup vs baseline: 1.2671x; 1.0540x over previous
//
#include <hip/hip_runtime.h>
#include <hip/hip_bf16.h>

#define N_TOK 8192
#define RREC 4352   // bytes/record: 4096 bf16-O (d-major [64][32]) + 128 f32-l + pad

typedef float f32x4  __attribute__((ext_vector_type(4)));
typedef float f32x16 __attribute__((ext_vector_type(16)));
typedef short bf16x8 __attribute__((ext_vector_type(8)));
typedef unsigned int u32x4 __attribute__((ext_vector_type(4)));

__device__ inline short f2bf(float f) {
    union { __hip_bfloat16 h; short s; } u;
    u.h = __float2bfloat16(f);
    return u.s;
}
__device__ inline unsigned cvtpk(float lo, float hi) {
    unsigned r;
    asm("v_cvt_pk_bf16_f32 %0, %1, %2" : "=v"(r) : "v"(lo), "v"(hi));
    return r;
}
__device__ inline void plswap(unsigned &a, unsigned &b) {
    asm("v_permlane32_swap_b32 %0, %1" : "+v"(a), "+v"(b));
}
// async global->LDS, 16B per lane; LDS dest = wave-uniform base + lane*16
__device__ inline void gload_lds16(const __hip_bfloat16* g, __hip_bfloat16* s) {
    __builtin_amdgcn_global_load_lds(
        (const __attribute__((address_space(1))) void*)(g),
        (__attribute__((address_space(3))) void*)(s), 16, 0, 0);
}

// Fragment-major tensor layouts (all 1 MiB):
//  Qf[((t*4 + kc)*64 + lane)*8 + j]      : Q[t*32 + (lane&31)][kc*16 + 8*(lane>>5) + j]
//  Kf[((c*8 + 4*hk + kc)*64 + lane)*8+j] : K[c*64 + 32*hk + (lane&31)][kc*16 + 8*(lane>>5) + j]
//  Vf[((c*8 + 4*hd + ks)*64 + lane)*8+j] : V[c*64 + ks*16 + 8*(lane>>5) + j][32*hd + (lane&31)]

// ---------------- kernel 0: weight convert/transpose (LDS tiled) ----
__global__ __launch_bounds__(256) void conv_kernel(
    const float* __restrict__ Wqkv,
    const float* __restrict__ Wout,
    __hip_bfloat16* __restrict__ Wt,      // [192][1024]
    __hip_bfloat16* __restrict__ WoT) {   // [1024][64]
    __shared__ float tile[32][33];
    const int t = threadIdx.x;
    const int cc = t & 31, rbase = t >> 5;
    const int b = blockIdx.x;
    if (b < 192) {
        const int r0 = (b & 31) * 32;   // k
        const int c0 = (b >> 5) * 32;   // n
        #pragma unroll
        for (int it = 0; it < 4; ++it) {
            const int rr = rbase + it * 8;
            tile[rr][cc] = Wqkv[(size_t)(r0 + rr) * 192 + c0 + cc];
        }
        __syncthreads();
        #pragma unroll
        for (int it = 0; it < 4; ++it) {
            const int rr = rbase + it * 8;
            Wt[(size_t)(c0 + rr) * 1024 + r0 + cc] = __float2bfloat16(tile[cc][rr]);
        }
    } else {
        const int bb = b - 192;
        const int r0 = (bb & 1) * 32;   // k (rows of Wout)
        const int c0 = (bb >> 1) * 32;  // n
        #pragma unroll
        for (int it = 0; it < 4; ++it) {
            const int rr = rbase + it * 8;
            tile[rr][cc] = Wout[(size_t)(r0 + rr) * 1024 + c0 + cc];
        }
        __syncthreads();
        #pragma unroll
        for (int it = 0; it < 4; ++it) {
            const int rr = rbase + it * 8;
            WoT[(size_t)(c0 + rr) * 64 + r0 + cc] = __float2bfloat16(tile[cc][rr]);
        }
    }
}

// ---------------- kernel 1: qkv = x @ Wqkv -------------------------
// LDS-staged double-buffered GEMM. BM=16, BN=192, BK=64, grid 512,
// 256 thr (4 waves) -> 2 independent blocks/CU (barrier overlap).
// Epilogue writes Qf/Kf/Vf in MFMA-fragment-major layout.
__global__ __launch_bounds__(256) void qkv_kernel(
    const float* __restrict__ x,
    const __hip_bfloat16* __restrict__ Wt,   // [192][1024]
    __hip_bfloat16* __restrict__ Qf,
    __hip_bfloat16* __restrict__ Kf,
    __hip_bfloat16* __restrict__ Vf) {
    __shared__ __hip_bfloat16 sA[2][16 * 64];
    __shared__ __hip_bfloat16 sB[2][192 * 64];
    __shared__ __hip_bfloat16 sV[64][20];
    const int tid = threadIdx.x;
    const int w = tid >> 6, lane = tid & 63;
    const int l16 = lane & 15, lq = lane >> 4;
    const int m0 = blockIdx.x * 16;

    const int ar = tid >> 4;
    const int ac = (tid & 15) >> 1;
    const int ah = tid & 1;
    const float* agp = x + (size_t)(m0 + ar) * 1024 + ac * 8 + ah * 4;
    const int aoff = ar * 64 + ((ac ^ (ar & 7)) * 8) + ah * 4;

    int boff[6];
    const __hip_bfloat16* bgp[6];
    #pragma unroll
    for (int i = 0; i < 6; ++i) {
        const int q = i * 256 + tid;
        const int r = q >> 3, c = q & 7;
        bgp[i] = Wt + (size_t)r * 1024 + c * 8;
        boff[i] = r * 64 + ((c ^ (r & 7)) * 8);
    }

    const int arow = l16;
    const int aswz0 = arow * 64 + ((lq ^ (arow & 7)) * 8);
    const int aswz1 = arow * 64 + (((4 + lq) ^ (arow & 7)) * 8);
    int bswz0[3], bswz1[3];
    #pragma unroll
    for (int j = 0; j < 3; ++j) {
        const int row = (w * 3 + j) * 16 + l16;
        bswz0[j] = row * 64 + ((lq ^ (row & 7)) * 8);
        bswz1[j] = row * 64 + (((4 + lq) ^ (row & 7)) * 8);
    }

    f32x4 acc[3];
    #pragma unroll
    for (int j = 0; j < 3; ++j) acc[j] = (f32x4)0.f;

    float4 areg;
    u32x4 breg[6];

    areg = *reinterpret_cast<const float4*>(agp);
    #pragma unroll
    for (int i = 0; i < 6; ++i)
        breg[i] = *reinterpret_cast<const u32x4*>(bgp[i]);
    {
        uint2 aw; aw.x = cvtpk(areg.x, areg.y); aw.y = cvtpk(areg.z, areg.w);
        *reinterpret_cast<uint2*>(&sA[0][aoff]) = aw;
        #pragma unroll
        for (int i = 0; i < 6; ++i)
            *reinterpret_cast<u32x4*>(&sB[0][boff[i]]) = breg[i];
    }
    __syncthreads();

    for (int ks = 0; ks < 16; ++ks) {
        const int cur = ks & 1;
        if (ks < 15) {
            areg = *reinterpret_cast<const float4*>(agp + (ks + 1) * 64);
            #pragma unroll
            for (int i = 0; i < 6; ++i)
                breg[i] = *reinterpret_cast<const u32x4*>(bgp[i] + (ks + 1) * 64);
        }
        bf16x8 af0 = *reinterpret_cast<const bf16x8*>(&sA[cur][aswz0]);
        bf16x8 af1 = *reinterpret_cast<const bf16x8*>(&sA[cur][aswz1]);
        #pragma unroll
        for (int j = 0; j < 3; ++j) {
            bf16x8 b0 = *reinterpret_cast<const bf16x8*>(&sB[cur][bswz0[j]]);
            bf16x8 b1 = *reinterpret_cast<const bf16x8*>(&sB[cur][bswz1[j]]);
            acc[j] = __builtin_amdgcn_mfma_f32_16x16x32_bf16(b0, af0, acc[j], 0, 0, 0);
            acc[j] = __builtin_amdgcn_mfma_f32_16x16x32_bf16(b1, af1, acc[j], 0, 0, 0);
        }
        if (ks < 15) {
            uint2 aw; aw.x = cvtpk(areg.x, areg.y); aw.y = cvtpk(areg.z, areg.w);
            *reinterpret_cast<uint2*>(&sA[cur ^ 1][aoff]) = aw;
            #pragma unroll
            for (int i = 0; i < 6; ++i)
                *reinterpret_cast<u32x4*>(&sB[cur ^ 1][boff[i]]) = breg[i];
        }
        __syncthreads();
    }

    const int row = m0 + l16;
    #pragma unroll
    for (int j = 0; j < 3; ++j) {
        const int nt = w * 3 + j;
        const int nb = nt * 16 + 4 * lq;
        if (nt < 4) {
            const int tq = row >> 5, lr = row & 31;
            const int kc = nb >> 4, hi2 = (nb >> 3) & 1, jj = nb & 7;
            short4 qs;
            qs.x = f2bf(acc[j][0] * 0.18033688011112042f);
            qs.y = f2bf(acc[j][1] * 0.18033688011112042f);
            qs.z = f2bf(acc[j][2] * 0.18033688011112042f);
            qs.w = f2bf(acc[j][3] * 0.18033688011112042f);
            *reinterpret_cast<short4*>(Qf + ((size_t)(tq * 4 + kc) * 64 + lr + 32 * hi2) * 8 + jj) = qs;
        } else if (nt < 8) {
            const int col = nb - 64;
            const int c = row >> 6, rr = row & 63, hk = rr >> 5, lr = rr & 31;
            const int kc = col >> 4, hi2 = (col >> 3) & 1, jj = col & 7;
            short4 ks4;
            ks4.x = f2bf(acc[j][0]); ks4.y = f2bf(acc[j][1]);
            ks4.z = f2bf(acc[j][2]); ks4.w = f2bf(acc[j][3]);
            *reinterpret_cast<short4*>(Kf + ((size_t)(c * 8 + 4 * hk + kc) * 64 + lr + 32 * hi2) * 8 + jj) = ks4;
        } else {
            #pragma unroll
            for (int r = 0; r < 4; ++r)
                sV[nb + r - 128][l16] = __float2bfloat16(acc[j][r]);
        }
    }
    __syncthreads();
    const int vd = tid >> 2, vm = (tid & 3) * 4;
    short4 vv = *reinterpret_cast<const short4*>(&sV[vd][vm]);
    const int kv = m0 + vm;
    const int c = kv >> 6, ks2 = (kv >> 4) & 3, hi2 = (kv >> 3) & 1, jj = kv & 7;
    *reinterpret_cast<short4*>(Vf + ((size_t)(c * 8 + 4 * (vd >> 5) + ks2) * 64 + (vd & 31) + 32 * hi2) * 8 + jj) = vv;
}

// ---------------- kernel 2: causal flash attention (glds-staged) ---
// Block = 512 thr / 8 waves covering 4 q-tiles: wave w -> tile
// tq = qb*4 + (w>>1), kv-half h = w&1. Grid 512 = 64 qb x 8 splits,
// snake-ordered. glds double-buffered K/V staging; FIXED-MAX softmax;
// bf16-normalized partial record (tq, s*2+h) per wave.
__global__ __launch_bounds__(512, 4) void attn_kernel(
    const __hip_bfloat16* __restrict__ Qf,
    const __hip_bfloat16* __restrict__ Kf,
    const __hip_bfloat16* __restrict__ Vf,
    char* __restrict__ Part) {  // [256 tiles][16 recs][RREC]
    __shared__ __hip_bfloat16 sK[2][4096];
    __shared__ __hip_bfloat16 sV2[2][4096];
    const int tid = threadIdx.x;
    const int w = tid >> 6, lane = tid & 63;
    const int l31 = lane & 31, hi = lane >> 5;
    const int bid = blockIdx.x;
    const int qb = (bid < 256) ? (63 - (bid >> 3)) : ((bid - 256) >> 3);
    const int s = bid & 7;
    const int tsub = w >> 1, h = w & 1;
    const int tq = qb * 4 + tsub;
    const int q0 = tq * 32;
    const int qabs = q0 + l31;
    const int CtB = 2 * qb + 2;
    const int nst = (CtB > s) ? ((CtB - s + 7) >> 3) : 0;

    bf16x8 qf[4];
    #pragma unroll
    for (int kc = 0; kc < 4; ++kc)
        qf[kc] = *reinterpret_cast<const bf16x8*>(
            Qf + ((size_t)(tq * 4 + kc) * 64 + lane) * 8);

    float l = 0.f;
    f32x16 Oa = (f32x16)0.f, Oc = (f32x16)0.f;

    const size_t gofs = (size_t)w * 512 + lane * 8;

    if (nst > 0) gload_lds16(Kf + (size_t)s * 4096 + gofs, &sK[0][w * 512]),
                 gload_lds16(Vf + (size_t)s * 4096 + gofs, &sV2[0][w * 512]);
    __syncthreads();

    int cur = 0;
    for (int st = 0; st < nst; ++st) {
        const int c = s + st * 8;
        if (st + 1 < nst) {
            gload_lds16(Kf + (size_t)(c + 8) * 4096 + gofs, &sK[cur ^ 1][w * 512]);
            gload_lds16(Vf + (size_t)(c + 8) * 4096 + gofs, &sV2[cur ^ 1][w * 512]);
        }

        const int kv0h = c * 64 + h * 32;
        if (kv0h <= q0 + 31) {
            f32x16 Sa = (f32x16)(-16.f);
            #pragma unroll
            for (int kc = 0; kc < 4; ++kc) {
                bf16x8 ka = *reinterpret_cast<const bf16x8*>(
                    &sK[cur][((4 * h + kc) * 64 + lane) * 8]);
                Sa = __builtin_amdgcn_mfma_f32_32x32x16_bf16(ka, qf[kc], Sa, 0, 0, 0);
            }

            if (kv0h + 32 > q0) {
                #pragma unroll
                for (int r = 0; r < 16; ++r) {
                    const int rowk = (r & 3) + 8 * (r >> 2) + 4 * hi;
                    if (kv0h + rowk > qabs) Sa[r] = -1.0e30f;
                }
            }

            #pragma unroll
            for (int r = 0; r < 16; ++r) Sa[r] = exp2f(Sa[r]);
            float s8[8];
            #pragma unroll
            for (int j = 0; j < 8; ++j) s8[j] = Sa[2 * j] + Sa[2 * j + 1];
            #pragma unroll
            for (int j = 0; j < 4; ++j) s8[j] += s8[j + 4];
            float ps = (s8[0] + s8[2]) + (s8[1] + s8[3]);
            ps += __shfl_xor(ps, 32);
            l += ps;

            bf16x8 F0, F1;
            {
                unsigned a0 = cvtpk(Sa[0], Sa[1]),  a1 = cvtpk(Sa[2], Sa[3]);
                unsigned a2 = cvtpk(Sa[4], Sa[5]),  a3 = cvtpk(Sa[6], Sa[7]);
                plswap(a0, a2); plswap(a1, a3);
                u32x4 w0; w0[0] = a0; w0[1] = a1; w0[2] = a2; w0[3] = a3;
                F0 = __builtin_bit_cast(bf16x8, w0);
                unsigned b0 = cvtpk(Sa[8], Sa[9]),  b1 = cvtpk(Sa[10], Sa[11]);
                unsigned b2 = cvtpk(Sa[12], Sa[13]), b3 = cvtpk(Sa[14], Sa[15]);
                plswap(b0, b2); plswap(b1, b3);
                u32x4 w1; w1[0] = b0; w1[1] = b1; w1[2] = b2; w1[3] = b3;
                F1 = __builtin_bit_cast(bf16x8, w1);
            }
            #pragma unroll
            for (int ks = 0; ks < 2; ++ks) {
                bf16x8 Fk = ks ? F1 : F0;
                bf16x8 v0 = *reinterpret_cast<const bf16x8*>(
                    &sV2[cur][((2 * h + ks) * 64 + lane) * 8]);
                bf16x8 v1 = *reinterpret_cast<const bf16x8*>(
                    &sV2[cur][((4 + 2 * h + ks) * 64 + lane) * 8]);
                Oa = __builtin_amdgcn_mfma_f32_32x32x16_bf16(v0, Fk, Oa, 0, 0, 0);
                Oc = __builtin_amdgcn_mfma_f32_32x32x16_bf16(v1, Fk, Oc, 0, 0, 0);
            }
        }

        __syncthreads();
        cur ^= 1;
    }

    char* rec = Part + ((size_t)tq * 16 + s * 2 + h) * RREC;
    __hip_bfloat16* On = (__hip_bfloat16*)rec;
    const float invl = (l > 0.f) ? (1.0f / l) : 0.f;
    #pragma unroll
    for (int r = 0; r < 16; ++r) {
        const int d = (r & 3) + 8 * (r >> 2) + 4 * hi;
        On[d * 32 + l31]        = __float2bfloat16(Oa[r] * invl);
        On[(d + 32) * 32 + l31] = __float2bfloat16(Oc[r] * invl);
    }
    if (hi == 0) ((float*)(rec + 4096))[l31] = l;
}

// ---------------- kernel 3: fused merge + out ----------------------
// grid 256: block = q-tile t (32 rows) x ALL 1024 cols. Phase 1 merges
// the 16 Part records into sOb[32][72] bf16 (padded: 144B row pitch
// breaks the 16-way bank conflict on row-strided A-frag reads, keeps
// 16B alignment). Phase 2: swapped-operand MFMA GEMM, A from LDS,
// wave w owns cols w*256..w*256+255. Kills merge launch + Ob buffer.
__global__ __launch_bounds__(256) void mo_kernel(
    const char* __restrict__ Part,
    const __hip_bfloat16* __restrict__ WoT,
    const float* __restrict__ bout,
    float* __restrict__ out) {
    __shared__ __hip_bfloat16 sOb[32][72];
    const int tid = threadIdx.x;
    const int t = blockIdx.x, q0 = t * 32;
    const char* base = Part + (size_t)t * 16 * RREC;

    // phase 1: merge 16 records -> sOb[qq][d]
    for (int e = tid; e < 2048; e += 256) {
        const int qq = e & 31, d = e >> 5;
        float ll = 0.f, oo = 0.f;
        #pragma unroll
        for (int rid = 0; rid < 16; ++rid) {
            const char* rec = base + rid * RREC;
            const float ls = ((const float*)(rec + 4096))[qq];
            ll += ls;
            oo += ls * __bfloat162float(((const __hip_bfloat16*)rec)[d * 32 + qq]);
        }
        sOb[qq][d] = __float2bfloat16(oo / ll);
    }
    __syncthreads();

    // phase 2: out rows q0..q0+31, cols w*256..w*256+255
    const int w = tid >> 6, lane = tid & 63;
    const int l16 = lane & 15, lq = lane >> 4;
    const int colq = w * 256;

    for (int nt = 0; nt < 16; ++nt) {
        const int cb = colq + nt * 16;
        const __hip_bfloat16* wrow = WoT + (size_t)(cb + l16) * 64;
        bf16x8 b0 = *reinterpret_cast<const bf16x8*>(wrow + 8 * lq);
        bf16x8 b1 = *reinterpret_cast<const bf16x8*>(wrow + 32 + 8 * lq);
        const int nb = cb + 4 * lq;
        float4 bb = *reinterpret_cast<const float4*>(bout + nb);
        #pragma unroll
        for (int rt = 0; rt < 2; ++rt) {
            const int arow = rt * 16 + l16;
            bf16x8 a0 = *reinterpret_cast<const bf16x8*>(&sOb[arow][8 * lq]);
            bf16x8 a1 = *reinterpret_cast<const bf16x8*>(&sOb[arow][32 + 8 * lq]);
            f32x4 acc = (f32x4)0.f;
            acc = __builtin_amdgcn_mfma_f32_16x16x32_bf16(b0, a0, acc, 0, 0, 0);
            acc = __builtin_amdgcn_mfma_f32_16x16x32_bf16(b1, a1, acc, 0, 0, 0);
            const int row = q0 + rt * 16 + l16;
            float4 res;
            res.x = acc[0] + bb.x; res.y = acc[1] + bb.y;
            res.z = acc[2] + bb.z; res.w = acc[3] + bb.w;
            *reinterpret_cast<float4*>(out + (size_t)row * 1024 + nb) = res;
        }
    }
}

// ---------------- launch -------------------------------------------
extern "C" void kernel_launch(void* const* d_in, const int* in_sizes, int n_in,
                              void* d_out, int out_size, void* d_ws, size_t ws_size,
                              hipStream_t stream) {
    const float* x    = (const float*)d_in[0];
    const float* Wqkv = (const float*)d_in[1];
    const float* Wout = (const float*)d_in[2];
    const float* bout = (const float*)d_in[3];
    float* out = (float*)d_out;

    char* ws = (char*)d_ws;
    __hip_bfloat16* Wt  = (__hip_bfloat16*)(ws);                 // 393216 B
    __hip_bfloat16* WoT = (__hip_bfloat16*)(ws + 393216);        // 131072 B
    __hip_bfloat16* Qf  = (__hip_bfloat16*)(ws + 524288);        // 1 MiB
    __hip_bfloat16* Kf  = (__hip_bfloat16*)(ws + 1572864);       // 1 MiB
    __hip_bfloat16* Vf  = (__hip_bfloat16*)(ws + 2621440);       // 1 MiB
    char*           Part = ws + 4718592;                         // 17.8 MB

    conv_kernel<<<256, 256, 0, stream>>>(Wqkv, Wout, Wt, WoT);
    qkv_kernel<<<512, 256, 0, stream>>>(x, Wt, Qf, Kf, Vf);
    attn_kernel<<<512, 512, 0, stream>>>(Qf, Kf, Vf, Part);
    mo_kernel<<<256, 256, 0, stream>>>(Part, WoT, bout, out);
}

// Round 20
// 65.353 us; speedup vs baseline: 1.2818x; 1.0116x over previous
//
#include <hip/hip_runtime.h>
#include <hip/hip_bf16.h>

#define N_TOK 8192
#define RREC 4352   // bytes/record: 4096 bf16-O (d-major [64][32], UNNORMALIZED) + 128 f32-l + pad

typedef float f32x4  __attribute__((ext_vector_type(4)));
typedef float f32x16 __attribute__((ext_vector_type(16)));
typedef short bf16x8 __attribute__((ext_vector_type(8)));
typedef unsigned int u32x4 __attribute__((ext_vector_type(4)));

__device__ inline short f2bf(float f) {
    union { __hip_bfloat16 h; short s; } u;
    u.h = __float2bfloat16(f);
    return u.s;
}
__device__ inline unsigned cvtpk(float lo, float hi) {
    unsigned r;
    asm("v_cvt_pk_bf16_f32 %0, %1, %2" : "=v"(r) : "v"(lo), "v"(hi));
    return r;
}
__device__ inline void plswap(unsigned &a, unsigned &b) {
    asm("v_permlane32_swap_b32 %0, %1" : "+v"(a), "+v"(b));
}
// async global->LDS, 16B per lane; LDS dest = wave-uniform base + lane*16
__device__ inline void gload_lds16(const __hip_bfloat16* g, __hip_bfloat16* s) {
    __builtin_amdgcn_global_load_lds(
        (const __attribute__((address_space(1))) void*)(g),
        (__attribute__((address_space(3))) void*)(s), 16, 0, 0);
}

// Fragment-major tensor layouts (all 1 MiB):
//  Qf[((t*4 + kc)*64 + lane)*8 + j]      : Q[t*32 + (lane&31)][kc*16 + 8*(lane>>5) + j]
//  Kf[((c*8 + 4*hk + kc)*64 + lane)*8+j] : K[c*64 + 32*hk + (lane&31)][kc*16 + 8*(lane>>5) + j]
//  Vf[((c*8 + 4*hd + ks)*64 + lane)*8+j] : V[c*64 + ks*16 + 8*(lane>>5) + j][32*hd + (lane&31)]

// ---------------- kernel 0: weight convert/transpose (LDS tiled) ----
__global__ __launch_bounds__(256) void conv_kernel(
    const float* __restrict__ Wqkv,
    const float* __restrict__ Wout,
    __hip_bfloat16* __restrict__ Wt,      // [192][1024]
    __hip_bfloat16* __restrict__ WoT) {   // [1024][64]
    __shared__ float tile[32][33];
    const int t = threadIdx.x;
    const int cc = t & 31, rbase = t >> 5;
    const int b = blockIdx.x;
    if (b < 192) {
        const int r0 = (b & 31) * 32;   // k
        const int c0 = (b >> 5) * 32;   // n
        #pragma unroll
        for (int it = 0; it < 4; ++it) {
            const int rr = rbase + it * 8;
            tile[rr][cc] = Wqkv[(size_t)(r0 + rr) * 192 + c0 + cc];
        }
        __syncthreads();
        #pragma unroll
        for (int it = 0; it < 4; ++it) {
            const int rr = rbase + it * 8;
            Wt[(size_t)(c0 + rr) * 1024 + r0 + cc] = __float2bfloat16(tile[cc][rr]);
        }
    } else {
        const int bb = b - 192;
        const int r0 = (bb & 1) * 32;   // k (rows of Wout)
        const int c0 = (bb >> 1) * 32;  // n
        #pragma unroll
        for (int it = 0; it < 4; ++it) {
            const int rr = rbase + it * 8;
            tile[rr][cc] = Wout[(size_t)(r0 + rr) * 1024 + c0 + cc];
        }
        __syncthreads();
        #pragma unroll
        for (int it = 0; it < 4; ++it) {
            const int rr = rbase + it * 8;
            WoT[(size_t)(c0 + rr) * 64 + r0 + cc] = __float2bfloat16(tile[cc][rr]);
        }
    }
}

// ---------------- kernel 1: qkv = x @ Wqkv -------------------------
// LDS-staged double-buffered GEMM. BM=16, BN=192, BK=64, grid 512,
// 256 thr (4 waves) -> 2 independent blocks/CU (barrier overlap).
// Epilogue writes Qf/Kf/Vf in MFMA-fragment-major layout.
__global__ __launch_bounds__(256) void qkv_kernel(
    const float* __restrict__ x,
    const __hip_bfloat16* __restrict__ Wt,   // [192][1024]
    __hip_bfloat16* __restrict__ Qf,
    __hip_bfloat16* __restrict__ Kf,
    __hip_bfloat16* __restrict__ Vf) {
    __shared__ __hip_bfloat16 sA[2][16 * 64];
    __shared__ __hip_bfloat16 sB[2][192 * 64];
    __shared__ __hip_bfloat16 sV[64][20];
    const int tid = threadIdx.x;
    const int w = tid >> 6, lane = tid & 63;
    const int l16 = lane & 15, lq = lane >> 4;
    const int m0 = blockIdx.x * 16;

    const int ar = tid >> 4;
    const int ac = (tid & 15) >> 1;
    const int ah = tid & 1;
    const float* agp = x + (size_t)(m0 + ar) * 1024 + ac * 8 + ah * 4;
    const int aoff = ar * 64 + ((ac ^ (ar & 7)) * 8) + ah * 4;

    int boff[6];
    const __hip_bfloat16* bgp[6];
    #pragma unroll
    for (int i = 0; i < 6; ++i) {
        const int q = i * 256 + tid;
        const int r = q >> 3, c = q & 7;
        bgp[i] = Wt + (size_t)r * 1024 + c * 8;
        boff[i] = r * 64 + ((c ^ (r & 7)) * 8);
    }

    const int arow = l16;
    const int aswz0 = arow * 64 + ((lq ^ (arow & 7)) * 8);
    const int aswz1 = arow * 64 + (((4 + lq) ^ (arow & 7)) * 8);
    int bswz0[3], bswz1[3];
    #pragma unroll
    for (int j = 0; j < 3; ++j) {
        const int row = (w * 3 + j) * 16 + l16;
        bswz0[j] = row * 64 + ((lq ^ (row & 7)) * 8);
        bswz1[j] = row * 64 + (((4 + lq) ^ (row & 7)) * 8);
    }

    f32x4 acc[3];
    #pragma unroll
    for (int j = 0; j < 3; ++j) acc[j] = (f32x4)0.f;

    float4 areg;
    u32x4 breg[6];

    areg = *reinterpret_cast<const float4*>(agp);
    #pragma unroll
    for (int i = 0; i < 6; ++i)
        breg[i] = *reinterpret_cast<const u32x4*>(bgp[i]);
    {
        uint2 aw; aw.x = cvtpk(areg.x, areg.y); aw.y = cvtpk(areg.z, areg.w);
        *reinterpret_cast<uint2*>(&sA[0][aoff]) = aw;
        #pragma unroll
        for (int i = 0; i < 6; ++i)
            *reinterpret_cast<u32x4*>(&sB[0][boff[i]]) = breg[i];
    }
    __syncthreads();

    for (int ks = 0; ks < 16; ++ks) {
        const int cur = ks & 1;
        if (ks < 15) {
            areg = *reinterpret_cast<const float4*>(agp + (ks + 1) * 64);
            #pragma unroll
            for (int i = 0; i < 6; ++i)
                breg[i] = *reinterpret_cast<const u32x4*>(bgp[i] + (ks + 1) * 64);
        }
        bf16x8 af0 = *reinterpret_cast<const bf16x8*>(&sA[cur][aswz0]);
        bf16x8 af1 = *reinterpret_cast<const bf16x8*>(&sA[cur][aswz1]);
        #pragma unroll
        for (int j = 0; j < 3; ++j) {
            bf16x8 b0 = *reinterpret_cast<const bf16x8*>(&sB[cur][bswz0[j]]);
            bf16x8 b1 = *reinterpret_cast<const bf16x8*>(&sB[cur][bswz1[j]]);
            acc[j] = __builtin_amdgcn_mfma_f32_16x16x32_bf16(b0, af0, acc[j], 0, 0, 0);
            acc[j] = __builtin_amdgcn_mfma_f32_16x16x32_bf16(b1, af1, acc[j], 0, 0, 0);
        }
        if (ks < 15) {
            uint2 aw; aw.x = cvtpk(areg.x, areg.y); aw.y = cvtpk(areg.z, areg.w);
            *reinterpret_cast<uint2*>(&sA[cur ^ 1][aoff]) = aw;
            #pragma unroll
            for (int i = 0; i < 6; ++i)
                *reinterpret_cast<u32x4*>(&sB[cur ^ 1][boff[i]]) = breg[i];
        }
        __syncthreads();
    }

    const int row = m0 + l16;
    #pragma unroll
    for (int j = 0; j < 3; ++j) {
        const int nt = w * 3 + j;
        const int nb = nt * 16 + 4 * lq;
        if (nt < 4) {
            const int tq = row >> 5, lr = row & 31;
            const int kc = nb >> 4, hi2 = (nb >> 3) & 1, jj = nb & 7;
            short4 qs;
            qs.x = f2bf(acc[j][0] * 0.18033688011112042f);
            qs.y = f2bf(acc[j][1] * 0.18033688011112042f);
            qs.z = f2bf(acc[j][2] * 0.18033688011112042f);
            qs.w = f2bf(acc[j][3] * 0.18033688011112042f);
            *reinterpret_cast<short4*>(Qf + ((size_t)(tq * 4 + kc) * 64 + lr + 32 * hi2) * 8 + jj) = qs;
        } else if (nt < 8) {
            const int col = nb - 64;
            const int c = row >> 6, rr = row & 63, hk = rr >> 5, lr = rr & 31;
            const int kc = col >> 4, hi2 = (col >> 3) & 1, jj = col & 7;
            short4 ks4;
            ks4.x = f2bf(acc[j][0]); ks4.y = f2bf(acc[j][1]);
            ks4.z = f2bf(acc[j][2]); ks4.w = f2bf(acc[j][3]);
            *reinterpret_cast<short4*>(Kf + ((size_t)(c * 8 + 4 * hk + kc) * 64 + lr + 32 * hi2) * 8 + jj) = ks4;
        } else {
            #pragma unroll
            for (int r = 0; r < 4; ++r)
                sV[nb + r - 128][l16] = __float2bfloat16(acc[j][r]);
        }
    }
    __syncthreads();
    const int vd = tid >> 2, vm = (tid & 3) * 4;
    short4 vv = *reinterpret_cast<const short4*>(&sV[vd][vm]);
    const int kv = m0 + vm;
    const int c = kv >> 6, ks2 = (kv >> 4) & 3, hi2 = (kv >> 3) & 1, jj = kv & 7;
    *reinterpret_cast<short4*>(Vf + ((size_t)(c * 8 + 4 * (vd >> 5) + ks2) * 64 + (vd & 31) + 32 * hi2) * 8 + jj) = vv;
}

// ---------------- kernel 2: causal flash attention (glds-staged) ---
// Block = 512 thr / 8 waves covering 4 q-tiles: wave w -> tile
// tq = qb*4 + (w>>1), kv-half h = w&1. Grid 512 = 64 qb x 8 splits,
// snake-ordered. glds double-buffered K/V staging; FIXED-MAX softmax.
// NEW: the two h-halves of each (tq,s) COMBINE IN LDS (plain sums under
// fixed-max) and h=0 writes ONE unnormalized record -> Part halved.
__global__ __launch_bounds__(512, 4) void attn_kernel(
    const __hip_bfloat16* __restrict__ Qf,
    const __hip_bfloat16* __restrict__ Kf,
    const __hip_bfloat16* __restrict__ Vf,
    char* __restrict__ Part) {  // [256 tiles][8 recs][RREC]
    __shared__ __hip_bfloat16 sK[2][4096];
    __shared__ __hip_bfloat16 sV2[2][4096];
    const int tid = threadIdx.x;
    const int w = tid >> 6, lane = tid & 63;
    const int l31 = lane & 31, hi = lane >> 5;
    const int bid = blockIdx.x;
    const int qb = (bid < 256) ? (63 - (bid >> 3)) : ((bid - 256) >> 3);
    const int s = bid & 7;
    const int tsub = w >> 1, h = w & 1;
    const int tq = qb * 4 + tsub;
    const int q0 = tq * 32;
    const int qabs = q0 + l31;
    const int CtB = 2 * qb + 2;
    const int nst = (CtB > s) ? ((CtB - s + 7) >> 3) : 0;

    bf16x8 qf[4];
    #pragma unroll
    for (int kc = 0; kc < 4; ++kc)
        qf[kc] = *reinterpret_cast<const bf16x8*>(
            Qf + ((size_t)(tq * 4 + kc) * 64 + lane) * 8);

    float l = 0.f;
    f32x16 Oa = (f32x16)0.f, Oc = (f32x16)0.f;

    const size_t gofs = (size_t)w * 512 + lane * 8;

    if (nst > 0) gload_lds16(Kf + (size_t)s * 4096 + gofs, &sK[0][w * 512]),
                 gload_lds16(Vf + (size_t)s * 4096 + gofs, &sV2[0][w * 512]);
    __syncthreads();

    int cur = 0;
    for (int st = 0; st < nst; ++st) {
        const int c = s + st * 8;
        if (st + 1 < nst) {
            gload_lds16(Kf + (size_t)(c + 8) * 4096 + gofs, &sK[cur ^ 1][w * 512]);
            gload_lds16(Vf + (size_t)(c + 8) * 4096 + gofs, &sV2[cur ^ 1][w * 512]);
        }

        const int kv0h = c * 64 + h * 32;
        if (kv0h <= q0 + 31) {
            f32x16 Sa = (f32x16)(-16.f);
            #pragma unroll
            for (int kc = 0; kc < 4; ++kc) {
                bf16x8 ka = *reinterpret_cast<const bf16x8*>(
                    &sK[cur][((4 * h + kc) * 64 + lane) * 8]);
                Sa = __builtin_amdgcn_mfma_f32_32x32x16_bf16(ka, qf[kc], Sa, 0, 0, 0);
            }

            if (kv0h + 32 > q0) {
                #pragma unroll
                for (int r = 0; r < 16; ++r) {
                    const int rowk = (r & 3) + 8 * (r >> 2) + 4 * hi;
                    if (kv0h + rowk > qabs) Sa[r] = -1.0e30f;
                }
            }

            #pragma unroll
            for (int r = 0; r < 16; ++r) Sa[r] = exp2f(Sa[r]);
            float s8[8];
            #pragma unroll
            for (int j = 0; j < 8; ++j) s8[j] = Sa[2 * j] + Sa[2 * j + 1];
            #pragma unroll
            for (int j = 0; j < 4; ++j) s8[j] += s8[j + 4];
            float ps = (s8[0] + s8[2]) + (s8[1] + s8[3]);
            ps += __shfl_xor(ps, 32);
            l += ps;

            bf16x8 F0, F1;
            {
                unsigned a0 = cvtpk(Sa[0], Sa[1]),  a1 = cvtpk(Sa[2], Sa[3]);
                unsigned a2 = cvtpk(Sa[4], Sa[5]),  a3 = cvtpk(Sa[6], Sa[7]);
                plswap(a0, a2); plswap(a1, a3);
                u32x4 w0; w0[0] = a0; w0[1] = a1; w0[2] = a2; w0[3] = a3;
                F0 = __builtin_bit_cast(bf16x8, w0);
                unsigned b0 = cvtpk(Sa[8], Sa[9]),  b1 = cvtpk(Sa[10], Sa[11]);
                unsigned b2 = cvtpk(Sa[12], Sa[13]), b3 = cvtpk(Sa[14], Sa[15]);
                plswap(b0, b2); plswap(b1, b3);
                u32x4 w1; w1[0] = b0; w1[1] = b1; w1[2] = b2; w1[3] = b3;
                F1 = __builtin_bit_cast(bf16x8, w1);
            }
            #pragma unroll
            for (int ks = 0; ks < 2; ++ks) {
                bf16x8 Fk = ks ? F1 : F0;
                bf16x8 v0 = *reinterpret_cast<const bf16x8*>(
                    &sV2[cur][((2 * h + ks) * 64 + lane) * 8]);
                bf16x8 v1 = *reinterpret_cast<const bf16x8*>(
                    &sV2[cur][((4 + 2 * h + ks) * 64 + lane) * 8]);
                Oa = __builtin_amdgcn_mfma_f32_32x32x16_bf16(v0, Fk, Oa, 0, 0, 0);
                Oc = __builtin_amdgcn_mfma_f32_32x32x16_bf16(v1, Fk, Oc, 0, 0, 0);
            }
        }

        __syncthreads();
        cur ^= 1;
    }

    // combine h-halves in LDS (plain sums; staging buffers now free).
    // h=1 exchanges O (bf16, tile t -> sK flat [t*2048, +2048)) and
    // l (f32, sV2 flat [t*32, +32)); h=0 adds and writes one record.
    __hip_bfloat16* exO = (__hip_bfloat16*)sK;
    float* exL = (float*)sV2;
    if (h == 1) {
        #pragma unroll
        for (int r = 0; r < 16; ++r) {
            const int d = (r & 3) + 8 * (r >> 2) + 4 * hi;
            exO[tsub * 2048 + d * 32 + l31]        = __float2bfloat16(Oa[r]);
            exO[tsub * 2048 + (d + 32) * 32 + l31] = __float2bfloat16(Oc[r]);
        }
        if (hi == 0) exL[tsub * 32 + l31] = l;
    }
    __syncthreads();
    if (h == 0) {
        char* rec = Part + ((size_t)tq * 8 + s) * RREC;
        __hip_bfloat16* On = (__hip_bfloat16*)rec;
        #pragma unroll
        for (int r = 0; r < 16; ++r) {
            const int d = (r & 3) + 8 * (r >> 2) + 4 * hi;
            On[d * 32 + l31] = __float2bfloat16(
                Oa[r] + __bfloat162float(exO[tsub * 2048 + d * 32 + l31]));
            On[(d + 32) * 32 + l31] = __float2bfloat16(
                Oc[r] + __bfloat162float(exO[tsub * 2048 + (d + 32) * 32 + l31]));
        }
        if (hi == 0)
            ((float*)(rec + 4096))[l31] = l + exL[tsub * 32 + l31];
    }
}

// ---------------- kernel 3: fused merge + out ----------------------
// grid 256: block = q-tile t. Phase 1 plain-sums the 8 unnormalized
// Part records into sOb[32][72] bf16 (padded row pitch). Phase 2:
// swapped-operand MFMA GEMM, A from LDS, wave w owns 256 cols.
__global__ __launch_bounds__(256) void mo_kernel(
    const char* __restrict__ Part,
    const __hip_bfloat16* __restrict__ WoT,
    const float* __restrict__ bout,
    float* __restrict__ out) {
    __shared__ __hip_bfloat16 sOb[32][72];
    const int tid = threadIdx.x;
    const int t = blockIdx.x, q0 = t * 32;
    const char* base = Part + (size_t)t * 8 * RREC;

    // phase 1: merge 8 records (plain sums) -> sOb[qq][d]
    for (int e = tid; e < 2048; e += 256) {
        const int qq = e & 31, d = e >> 5;
        float ll = 0.f, oo = 0.f;
        #pragma unroll
        for (int rid = 0; rid < 8; ++rid) {
            const char* rec = base + rid * RREC;
            ll += ((const float*)(rec + 4096))[qq];
            oo += __bfloat162float(((const __hip_bfloat16*)rec)[d * 32 + qq]);
        }
        sOb[qq][d] = __float2bfloat16(oo / ll);
    }
    __syncthreads();

    // phase 2: out rows q0..q0+31, cols w*256..w*256+255
    const int w = tid >> 6, lane = tid & 63;
    const int l16 = lane & 15, lq = lane >> 4;
    const int colq = w * 256;

    for (int nt = 0; nt < 16; ++nt) {
        const int cb = colq + nt * 16;
        const __hip_bfloat16* wrow = WoT + (size_t)(cb + l16) * 64;
        bf16x8 b0 = *reinterpret_cast<const bf16x8*>(wrow + 8 * lq);
        bf16x8 b1 = *reinterpret_cast<const bf16x8*>(wrow + 32 + 8 * lq);
        const int nb = cb + 4 * lq;
        float4 bb = *reinterpret_cast<const float4*>(bout + nb);
        #pragma unroll
        for (int rt = 0; rt < 2; ++rt) {
            const int arow = rt * 16 + l16;
            bf16x8 a0 = *reinterpret_cast<const bf16x8*>(&sOb[arow][8 * lq]);
            bf16x8 a1 = *reinterpret_cast<const bf16x8*>(&sOb[arow][32 + 8 * lq]);
            f32x4 acc = (f32x4)0.f;
            acc = __builtin_amdgcn_mfma_f32_16x16x32_bf16(b0, a0, acc, 0, 0, 0);
            acc = __builtin_amdgcn_mfma_f32_16x16x32_bf16(b1, a1, acc, 0, 0, 0);
            const int row = q0 + rt * 16 + l16;
            float4 res;
            res.x = acc[0] + bb.x; res.y = acc[1] + bb.y;
            res.z = acc[2] + bb.z; res.w = acc[3] + bb.w;
            *reinterpret_cast<float4*>(out + (size_t)row * 1024 + nb) = res;
        }
    }
}

// ---------------- launch -------------------------------------------
extern "C" void kernel_launch(void* const* d_in, const int* in_sizes, int n_in,
                              void* d_out, int out_size, void* d_ws, size_t ws_size,
                              hipStream_t stream) {
    const float* x    = (const float*)d_in[0];
    const float* Wqkv = (const float*)d_in[1];
    const float* Wout = (const float*)d_in[2];
    const float* bout = (const float*)d_in[3];
    float* out = (float*)d_out;

    char* ws = (char*)d_ws;
    __hip_bfloat16* Wt  = (__hip_bfloat16*)(ws);                 // 393216 B
    __hip_bfloat16* WoT = (__hip_bfloat16*)(ws + 393216);        // 131072 B
    __hip_bfloat16* Qf  = (__hip_bfloat16*)(ws + 524288);        // 1 MiB
    __hip_bfloat16* Kf  = (__hip_bfloat16*)(ws + 1572864);       // 1 MiB
    __hip_bfloat16* Vf  = (__hip_bfloat16*)(ws + 2621440);       // 1 MiB
    char*           Part = ws + 4718592;                         // 256*8*4352 = 8.9 MB

    conv_kernel<<<256, 256, 0, stream>>>(Wqkv, Wout, Wt, WoT);
    qkv_kernel<<<512, 256, 0, stream>>>(x, Wt, Qf, Kf, Vf);
    attn_kernel<<<512, 512, 0, stream>>>(Qf, Kf, Vf, Part);
    mo_kernel<<<256, 256, 0, stream>>>(Part, WoT, bout, out);
}

// Round 21
// 63.506 us; speedup vs baseline: 1.3190x; 1.0291x over previous
//
#include <hip/hip_runtime.h>
#include <hip/hip_bf16.h>

#define N_TOK 8192
#define RREC 4352   // bytes/record: 4096 bf16-O (d-major [64][32], UNNORMALIZED) + 128 f32-l + pad

typedef float f32x4  __attribute__((ext_vector_type(4)));
typedef float f32x16 __attribute__((ext_vector_type(16)));
typedef short bf16x8 __attribute__((ext_vector_type(8)));
typedef unsigned int u32x4 __attribute__((ext_vector_type(4)));

__device__ inline short f2bf(float f) {
    union { __hip_bfloat16 h; short s; } u;
    u.h = __float2bfloat16(f);
    return u.s;
}
__device__ inline unsigned cvtpk(float lo, float hi) {
    unsigned r;
    asm("v_cvt_pk_bf16_f32 %0, %1, %2" : "=v"(r) : "v"(lo), "v"(hi));
    return r;
}
__device__ inline void plswap(unsigned &a, unsigned &b) {
    asm("v_permlane32_swap_b32 %0, %1" : "+v"(a), "+v"(b));
}
// async global->LDS, 16B per lane; LDS dest = wave-uniform base + lane*16
__device__ inline void gload_lds16(const __hip_bfloat16* g, __hip_bfloat16* s) {
    __builtin_amdgcn_global_load_lds(
        (const __attribute__((address_space(1))) void*)(g),
        (__attribute__((address_space(3))) void*)(s), 16, 0, 0);
}

// Fragment-major tensor layouts (all 1 MiB):
//  Qf[((t*4 + kc)*64 + lane)*8 + j]      : Q[t*32 + (lane&31)][kc*16 + 8*(lane>>5) + j]
//  Kf[((c*8 + 4*hk + kc)*64 + lane)*8+j] : K[c*64 + 32*hk + (lane&31)][kc*16 + 8*(lane>>5) + j]
//  Vf[((c*8 + 4*hd + ks)*64 + lane)*8+j] : V[c*64 + ks*16 + 8*(lane>>5) + j][32*hd + (lane&31)]

// ---------------- kernel 0: weight convert/transpose (LDS tiled) ----
__global__ __launch_bounds__(256) void conv_kernel(
    const float* __restrict__ Wqkv,
    const float* __restrict__ Wout,
    __hip_bfloat16* __restrict__ Wt,      // [192][1024]
    __hip_bfloat16* __restrict__ WoT) {   // [1024][64]
    __shared__ float tile[32][33];
    const int t = threadIdx.x;
    const int cc = t & 31, rbase = t >> 5;
    const int b = blockIdx.x;
    if (b < 192) {
        const int r0 = (b & 31) * 32;   // k
        const int c0 = (b >> 5) * 32;   // n
        #pragma unroll
        for (int it = 0; it < 4; ++it) {
            const int rr = rbase + it * 8;
            tile[rr][cc] = Wqkv[(size_t)(r0 + rr) * 192 + c0 + cc];
        }
        __syncthreads();
        #pragma unroll
        for (int it = 0; it < 4; ++it) {
            const int rr = rbase + it * 8;
            Wt[(size_t)(c0 + rr) * 1024 + r0 + cc] = __float2bfloat16(tile[cc][rr]);
        }
    } else {
        const int bb = b - 192;
        const int r0 = (bb & 1) * 32;   // k (rows of Wout)
        const int c0 = (bb >> 1) * 32;  // n
        #pragma unroll
        for (int it = 0; it < 4; ++it) {
            const int rr = rbase + it * 8;
            tile[rr][cc] = Wout[(size_t)(r0 + rr) * 1024 + c0 + cc];
        }
        __syncthreads();
        #pragma unroll
        for (int it = 0; it < 4; ++it) {
            const int rr = rbase + it * 8;
            WoT[(size_t)(c0 + rr) * 64 + r0 + cc] = __float2bfloat16(tile[cc][rr]);
        }
    }
}

// ---------------- kernel 1: qkv = x @ Wqkv -------------------------
// LDS-staged double-buffered GEMM. BM=16, BN=192, BK=64, grid 512,
// 256 thr (4 waves) -> 2 independent blocks/CU (barrier overlap).
// Epilogue writes Qf/Kf/Vf in MFMA-fragment-major layout.
__global__ __launch_bounds__(256) void qkv_kernel(
    const float* __restrict__ x,
    const __hip_bfloat16* __restrict__ Wt,   // [192][1024]
    __hip_bfloat16* __restrict__ Qf,
    __hip_bfloat16* __restrict__ Kf,
    __hip_bfloat16* __restrict__ Vf) {
    __shared__ __hip_bfloat16 sA[2][16 * 64];
    __shared__ __hip_bfloat16 sB[2][192 * 64];
    __shared__ __hip_bfloat16 sV[64][20];
    const int tid = threadIdx.x;
    const int w = tid >> 6, lane = tid & 63;
    const int l16 = lane & 15, lq = lane >> 4;
    const int m0 = blockIdx.x * 16;

    const int ar = tid >> 4;
    const int ac = (tid & 15) >> 1;
    const int ah = tid & 1;
    const float* agp = x + (size_t)(m0 + ar) * 1024 + ac * 8 + ah * 4;
    const int aoff = ar * 64 + ((ac ^ (ar & 7)) * 8) + ah * 4;

    int boff[6];
    const __hip_bfloat16* bgp[6];
    #pragma unroll
    for (int i = 0; i < 6; ++i) {
        const int q = i * 256 + tid;
        const int r = q >> 3, c = q & 7;
        bgp[i] = Wt + (size_t)r * 1024 + c * 8;
        boff[i] = r * 64 + ((c ^ (r & 7)) * 8);
    }

    const int arow = l16;
    const int aswz0 = arow * 64 + ((lq ^ (arow & 7)) * 8);
    const int aswz1 = arow * 64 + (((4 + lq) ^ (arow & 7)) * 8);
    int bswz0[3], bswz1[3];
    #pragma unroll
    for (int j = 0; j < 3; ++j) {
        const int row = (w * 3 + j) * 16 + l16;
        bswz0[j] = row * 64 + ((lq ^ (row & 7)) * 8);
        bswz1[j] = row * 64 + (((4 + lq) ^ (row & 7)) * 8);
    }

    f32x4 acc[3];
    #pragma unroll
    for (int j = 0; j < 3; ++j) acc[j] = (f32x4)0.f;

    float4 areg;
    u32x4 breg[6];

    areg = *reinterpret_cast<const float4*>(agp);
    #pragma unroll
    for (int i = 0; i < 6; ++i)
        breg[i] = *reinterpret_cast<const u32x4*>(bgp[i]);
    {
        uint2 aw; aw.x = cvtpk(areg.x, areg.y); aw.y = cvtpk(areg.z, areg.w);
        *reinterpret_cast<uint2*>(&sA[0][aoff]) = aw;
        #pragma unroll
        for (int i = 0; i < 6; ++i)
            *reinterpret_cast<u32x4*>(&sB[0][boff[i]]) = breg[i];
    }
    __syncthreads();

    for (int ks = 0; ks < 16; ++ks) {
        const int cur = ks & 1;
        if (ks < 15) {
            areg = *reinterpret_cast<const float4*>(agp + (ks + 1) * 64);
            #pragma unroll
            for (int i = 0; i < 6; ++i)
                breg[i] = *reinterpret_cast<const u32x4*>(bgp[i] + (ks + 1) * 64);
        }
        bf16x8 af0 = *reinterpret_cast<const bf16x8*>(&sA[cur][aswz0]);
        bf16x8 af1 = *reinterpret_cast<const bf16x8*>(&sA[cur][aswz1]);
        #pragma unroll
        for (int j = 0; j < 3; ++j) {
            bf16x8 b0 = *reinterpret_cast<const bf16x8*>(&sB[cur][bswz0[j]]);
            bf16x8 b1 = *reinterpret_cast<const bf16x8*>(&sB[cur][bswz1[j]]);
            acc[j] = __builtin_amdgcn_mfma_f32_16x16x32_bf16(b0, af0, acc[j], 0, 0, 0);
            acc[j] = __builtin_amdgcn_mfma_f32_16x16x32_bf16(b1, af1, acc[j], 0, 0, 0);
        }
        if (ks < 15) {
            uint2 aw; aw.x = cvtpk(areg.x, areg.y); aw.y = cvtpk(areg.z, areg.w);
            *reinterpret_cast<uint2*>(&sA[cur ^ 1][aoff]) = aw;
            #pragma unroll
            for (int i = 0; i < 6; ++i)
                *reinterpret_cast<u32x4*>(&sB[cur ^ 1][boff[i]]) = breg[i];
        }
        __syncthreads();
    }

    const int row = m0 + l16;
    #pragma unroll
    for (int j = 0; j < 3; ++j) {
        const int nt = w * 3 + j;
        const int nb = nt * 16 + 4 * lq;
        if (nt < 4) {
            const int tq = row >> 5, lr = row & 31;
            const int kc = nb >> 4, hi2 = (nb >> 3) & 1, jj = nb & 7;
            short4 qs;
            qs.x = f2bf(acc[j][0] * 0.18033688011112042f);
            qs.y = f2bf(acc[j][1] * 0.18033688011112042f);
            qs.z = f2bf(acc[j][2] * 0.18033688011112042f);
            qs.w = f2bf(acc[j][3] * 0.18033688011112042f);
            *reinterpret_cast<short4*>(Qf + ((size_t)(tq * 4 + kc) * 64 + lr + 32 * hi2) * 8 + jj) = qs;
        } else if (nt < 8) {
            const int col = nb - 64;
            const int c = row >> 6, rr = row & 63, hk = rr >> 5, lr = rr & 31;
            const int kc = col >> 4, hi2 = (col >> 3) & 1, jj = col & 7;
            short4 ks4;
            ks4.x = f2bf(acc[j][0]); ks4.y = f2bf(acc[j][1]);
            ks4.z = f2bf(acc[j][2]); ks4.w = f2bf(acc[j][3]);
            *reinterpret_cast<short4*>(Kf + ((size_t)(c * 8 + 4 * hk + kc) * 64 + lr + 32 * hi2) * 8 + jj) = ks4;
        } else {
            #pragma unroll
            for (int r = 0; r < 4; ++r)
                sV[nb + r - 128][l16] = __float2bfloat16(acc[j][r]);
        }
    }
    __syncthreads();
    const int vd = tid >> 2, vm = (tid & 3) * 4;
    short4 vv = *reinterpret_cast<const short4*>(&sV[vd][vm]);
    const int kv = m0 + vm;
    const int c = kv >> 6, ks2 = (kv >> 4) & 3, hi2 = (kv >> 3) & 1, jj = kv & 7;
    *reinterpret_cast<short4*>(Vf + ((size_t)(c * 8 + 4 * (vd >> 5) + ks2) * 64 + (vd & 31) + 32 * hi2) * 8 + jj) = vv;
}

// ---------------- kernel 2: causal flash attention (glds, 128-kv) --
// Block = 512 thr / 8 waves covering 4 q-tiles: wave w -> tile
// tq = qb*4 + (w>>1), kv-half h = w&1 (64 kv = orig chunk 2c+h).
// Grid 512 = 64 qb x 8 splits (128-kv chunks c = s + 8*st), snake-
// ordered. Stages HALVED vs 64-kv chunking (fewer barriers+drains);
// each wave runs its 64 kv as two sequential 32-kv sub-iterations
// (S regs reused -> VGPR flat). LDS 2x32KB (2 blocks/CU).
// FIXED-MAX softmax; h-halves combine in LDS; one unnorm record/(tq,s).
__global__ __launch_bounds__(512, 4) void attn_kernel(
    const __hip_bfloat16* __restrict__ Qf,
    const __hip_bfloat16* __restrict__ Kf,
    const __hip_bfloat16* __restrict__ Vf,
    char* __restrict__ Part) {  // [256 tiles][8 recs][RREC]
    __shared__ __hip_bfloat16 sK[2][8192];
    __shared__ __hip_bfloat16 sV2[2][8192];
    const int tid = threadIdx.x;
    const int w = tid >> 6, lane = tid & 63;
    const int l31 = lane & 31, hi = lane >> 5;
    const int bid = blockIdx.x;
    const int qb = (bid < 256) ? (63 - (bid >> 3)) : ((bid - 256) >> 3);
    const int s = bid & 7;
    const int tsub = w >> 1, h = w & 1;
    const int tq = qb * 4 + tsub;
    const int q0 = tq * 32;
    const int qabs = q0 + l31;
    const int Ct128 = qb + 1;                        // 128-kv chunks needed
    const int nst = (Ct128 > s) ? ((Ct128 - s + 7) >> 3) : 0;

    bf16x8 qf[4];
    #pragma unroll
    for (int kc = 0; kc < 4; ++kc)
        qf[kc] = *reinterpret_cast<const bf16x8*>(
            Qf + ((size_t)(tq * 4 + kc) * 64 + lane) * 8);

    float l = 0.f;
    f32x16 Oa = (f32x16)0.f, Oc = (f32x16)0.f;

    // staging: 128-kv chunk = 16KB K + 16KB V; thread covers 2x16B each
    const size_t g0 = (size_t)w * 512 + lane * 8;     // first half offset
    const size_t g1 = g0 + 4096;                      // second half offset

    if (nst > 0) {
        gload_lds16(Kf + (size_t)s * 8192 + g0, &sK[0][w * 512]);
        gload_lds16(Kf + (size_t)s * 8192 + g1, &sK[0][4096 + w * 512]);
        gload_lds16(Vf + (size_t)s * 8192 + g0, &sV2[0][w * 512]);
        gload_lds16(Vf + (size_t)s * 8192 + g1, &sV2[0][4096 + w * 512]);
    }
    __syncthreads();

    int cur = 0;
    for (int st = 0; st < nst; ++st) {
        const int c = s + st * 8;
        if (st + 1 < nst) {
            gload_lds16(Kf + (size_t)(c + 8) * 8192 + g0, &sK[cur ^ 1][w * 512]);
            gload_lds16(Kf + (size_t)(c + 8) * 8192 + g1, &sK[cur ^ 1][4096 + w * 512]);
            gload_lds16(Vf + (size_t)(c + 8) * 8192 + g0, &sV2[cur ^ 1][w * 512]);
            gload_lds16(Vf + (size_t)(c + 8) * 8192 + g1, &sV2[cur ^ 1][4096 + w * 512]);
        }

        // wave handles orig 64-kv chunk index 2c+h, at LDS base h*4096
        const int kvbase = (2 * c + h) * 64;
        #pragma unroll
        for (int half = 0; half < 2; ++half) {
            const int kv0h = kvbase + half * 32;
            if (kv0h > q0 + 31) continue;
            f32x16 Sa = (f32x16)(-16.f);
            #pragma unroll
            for (int kc = 0; kc < 4; ++kc) {
                bf16x8 ka = *reinterpret_cast<const bf16x8*>(
                    &sK[cur][h * 4096 + ((4 * half + kc) * 64 + lane) * 8]);
                Sa = __builtin_amdgcn_mfma_f32_32x32x16_bf16(ka, qf[kc], Sa, 0, 0, 0);
            }

            if (kv0h + 32 > q0) {
                #pragma unroll
                for (int r = 0; r < 16; ++r) {
                    const int rowk = (r & 3) + 8 * (r >> 2) + 4 * hi;
                    if (kv0h + rowk > qabs) Sa[r] = -1.0e30f;
                }
            }

            #pragma unroll
            for (int r = 0; r < 16; ++r) Sa[r] = exp2f(Sa[r]);
            float s8[8];
            #pragma unroll
            for (int j = 0; j < 8; ++j) s8[j] = Sa[2 * j] + Sa[2 * j + 1];
            #pragma unroll
            for (int j = 0; j < 4; ++j) s8[j] += s8[j + 4];
            float ps = (s8[0] + s8[2]) + (s8[1] + s8[3]);
            ps += __shfl_xor(ps, 32);
            l += ps;

            bf16x8 F0, F1;
            {
                unsigned a0 = cvtpk(Sa[0], Sa[1]),  a1 = cvtpk(Sa[2], Sa[3]);
                unsigned a2 = cvtpk(Sa[4], Sa[5]),  a3 = cvtpk(Sa[6], Sa[7]);
                plswap(a0, a2); plswap(a1, a3);
                u32x4 w0; w0[0] = a0; w0[1] = a1; w0[2] = a2; w0[3] = a3;
                F0 = __builtin_bit_cast(bf16x8, w0);
                unsigned b0 = cvtpk(Sa[8], Sa[9]),  b1 = cvtpk(Sa[10], Sa[11]);
                unsigned b2 = cvtpk(Sa[12], Sa[13]), b3 = cvtpk(Sa[14], Sa[15]);
                plswap(b0, b2); plswap(b1, b3);
                u32x4 w1; w1[0] = b0; w1[1] = b1; w1[2] = b2; w1[3] = b3;
                F1 = __builtin_bit_cast(bf16x8, w1);
            }
            #pragma unroll
            for (int ks = 0; ks < 2; ++ks) {
                bf16x8 Fk = ks ? F1 : F0;
                bf16x8 v0 = *reinterpret_cast<const bf16x8*>(
                    &sV2[cur][h * 4096 + ((2 * half + ks) * 64 + lane) * 8]);
                bf16x8 v1 = *reinterpret_cast<const bf16x8*>(
                    &sV2[cur][h * 4096 + ((4 + 2 * half + ks) * 64 + lane) * 8]);
                Oa = __builtin_amdgcn_mfma_f32_32x32x16_bf16(v0, Fk, Oa, 0, 0, 0);
                Oc = __builtin_amdgcn_mfma_f32_32x32x16_bf16(v1, Fk, Oc, 0, 0, 0);
            }
        }

        __syncthreads();
        cur ^= 1;
    }

    // combine h-halves in LDS (plain sums; staging buffers now free).
    __hip_bfloat16* exO = (__hip_bfloat16*)sK;
    float* exL = (float*)sV2;
    if (h == 1) {
        #pragma unroll
        for (int r = 0; r < 16; ++r) {
            const int d = (r & 3) + 8 * (r >> 2) + 4 * hi;
            exO[tsub * 2048 + d * 32 + l31]        = __float2bfloat16(Oa[r]);
            exO[tsub * 2048 + (d + 32) * 32 + l31] = __float2bfloat16(Oc[r]);
        }
        if (hi == 0) exL[tsub * 32 + l31] = l;
    }
    __syncthreads();
    if (h == 0) {
        char* rec = Part + ((size_t)tq * 8 + s) * RREC;
        __hip_bfloat16* On = (__hip_bfloat16*)rec;
        #pragma unroll
        for (int r = 0; r < 16; ++r) {
            const int d = (r & 3) + 8 * (r >> 2) + 4 * hi;
            On[d * 32 + l31] = __float2bfloat16(
                Oa[r] + __bfloat162float(exO[tsub * 2048 + d * 32 + l31]));
            On[(d + 32) * 32 + l31] = __float2bfloat16(
                Oc[r] + __bfloat162float(exO[tsub * 2048 + (d + 32) * 32 + l31]));
        }
        if (hi == 0)
            ((float*)(rec + 4096))[l31] = l + exL[tsub * 32 + l31];
    }
}

// ---------------- kernel 3: fused merge + out ----------------------
// grid 256: block = q-tile t. Phase 1 plain-sums the 8 unnormalized
// Part records into sOb[32][72] bf16 (padded row pitch). Phase 2:
// swapped-operand MFMA GEMM, A from LDS, wave w owns 256 cols.
__global__ __launch_bounds__(256) void mo_kernel(
    const char* __restrict__ Part,
    const __hip_bfloat16* __restrict__ WoT,
    const float* __restrict__ bout,
    float* __restrict__ out) {
    __shared__ __hip_bfloat16 sOb[32][72];
    const int tid = threadIdx.x;
    const int t = blockIdx.x, q0 = t * 32;
    const char* base = Part + (size_t)t * 8 * RREC;

    // phase 1: merge 8 records (plain sums) -> sOb[qq][d]
    for (int e = tid; e < 2048; e += 256) {
        const int qq = e & 31, d = e >> 5;
        float ll = 0.f, oo = 0.f;
        #pragma unroll
        for (int rid = 0; rid < 8; ++rid) {
            const char* rec = base + rid * RREC;
            ll += ((const float*)(rec + 4096))[qq];
            oo += __bfloat162float(((const __hip_bfloat16*)rec)[d * 32 + qq]);
        }
        sOb[qq][d] = __float2bfloat16(oo / ll);
    }
    __syncthreads();

    // phase 2: out rows q0..q0+31, cols w*256..w*256+255
    const int w = tid >> 6, lane = tid & 63;
    const int l16 = lane & 15, lq = lane >> 4;
    const int colq = w * 256;

    for (int nt = 0; nt < 16; ++nt) {
        const int cb = colq + nt * 16;
        const __hip_bfloat16* wrow = WoT + (size_t)(cb + l16) * 64;
        bf16x8 b0 = *reinterpret_cast<const bf16x8*>(wrow + 8 * lq);
        bf16x8 b1 = *reinterpret_cast<const bf16x8*>(wrow + 32 + 8 * lq);
        const int nb = cb + 4 * lq;
        float4 bb = *reinterpret_cast<const float4*>(bout + nb);
        #pragma unroll
        for (int rt = 0; rt < 2; ++rt) {
            const int arow = rt * 16 + l16;
            bf16x8 a0 = *reinterpret_cast<const bf16x8*>(&sOb[arow][8 * lq]);
            bf16x8 a1 = *reinterpret_cast<const bf16x8*>(&sOb[arow][32 + 8 * lq]);
            f32x4 acc = (f32x4)0.f;
            acc = __builtin_amdgcn_mfma_f32_16x16x32_bf16(b0, a0, acc, 0, 0, 0);
            acc = __builtin_amdgcn_mfma_f32_16x16x32_bf16(b1, a1, acc, 0, 0, 0);
            const int row = q0 + rt * 16 + l16;
            float4 res;
            res.x = acc[0] + bb.x; res.y = acc[1] + bb.y;
            res.z = acc[2] + bb.z; res.w = acc[3] + bb.w;
            *reinterpret_cast<float4*>(out + (size_t)row * 1024 + nb) = res;
        }
    }
}

// ---------------- launch -------------------------------------------
extern "C" void kernel_launch(void* const* d_in, const int* in_sizes, int n_in,
                              void* d_out, int out_size, void* d_ws, size_t ws_size,
                              hipStream_t stream) {
    const float* x    = (const float*)d_in[0];
    const float* Wqkv = (const float*)d_in[1];
    const float* Wout = (const float*)d_in[2];
    const float* bout = (const float*)d_in[3];
    float* out = (float*)d_out;

    char* ws = (char*)d_ws;
    __hip_bfloat16* Wt  = (__hip_bfloat16*)(ws);                 // 393216 B
    __hip_bfloat16* WoT = (__hip_bfloat16*)(ws + 393216);        // 131072 B
    __hip_bfloat16* Qf  = (__hip_bfloat16*)(ws + 524288);        // 1 MiB
    __hip_bfloat16* Kf  = (__hip_bfloat16*)(ws + 1572864);       // 1 MiB
    __hip_bfloat16* Vf  = (__hip_bfloat16*)(ws + 2621440);       // 1 MiB
    char*           Part = ws + 4718592;                         // 8.9 MB

    conv_kernel<<<256, 256, 0, stream>>>(Wqkv, Wout, Wt, WoT);
    qkv_kernel<<<512, 256, 0, stream>>>(x, Wt, Qf, Kf, Vf);
    attn_kernel<<<512, 512, 0, stream>>>(Qf, Kf, Vf, Part);
    mo_kernel<<<256, 256, 0, stream>>>(Part, WoT, bout, out);
}